// Round 6
// baseline (445.865 us; speedup 1.0000x reference)
//
#include <hip/hip_runtime.h>
#include <stdint.h>

#define D_DIM 256
#define NPAD  640   // 256 (W_lin) + 256 (W_res) + 8 (att_l) + 8 (att_r) + 112 zero pad -> 5 x 128 tiles

typedef __bf16 bf16x8 __attribute__((ext_vector_type(8)));
typedef float  f32x4  __attribute__((ext_vector_type(4)));

__device__ __forceinline__ float bf2f(unsigned short u) {
  union { unsigned int i; float f; } cv; cv.i = ((unsigned int)u) << 16; return cv.f;
}
__device__ __forceinline__ unsigned short f2bf(float f) {
  union { float f; unsigned int i; } cv; cv.f = f;
  unsigned int i = cv.i;
  unsigned int lsb = (i >> 16) & 1u;
  i += 0x7fffu + lsb;   // round-to-nearest-even
  return (unsigned short)(i >> 16);
}
__device__ __forceinline__ void gld16(const void* gptr, void* lptr) {
  __builtin_amdgcn_global_load_lds(
      (const __attribute__((address_space(1))) unsigned int*)gptr,
      (__attribute__((address_space(3))) unsigned int*)lptr, 16, 0, 0);
}

// ---------------- fused setup: [hist | cvt_feat | prep_bt] by block range ----------------
// hist blocks FIRST: they are atomic-latency-bound (8 independent RMWs in flight/thread)
// and overlap under the cvt/prep streaming blocks. No LDS anywhere in this kernel, so the
// round-2 fusion failure (hist blocks dragging a 32KB LDS alloc + gating MFMA tiles) does
// not apply here.
__global__ __launch_bounds__(256) void setup_fused(
    const float* __restrict__ feat, unsigned short* __restrict__ fb,
    const float* __restrict__ W_lin, const float* __restrict__ W_res,
    const float* __restrict__ att_l, const float* __restrict__ att_r,
    unsigned short* __restrict__ Bt, int nelem, int nb_hist, int nb_cvt,
    const int* __restrict__ dst, int* __restrict__ cnt, int* __restrict__ rank, int E) {
  int bid = blockIdx.x, t = threadIdx.x;
  if (bid < nb_hist) {
    int base = bid * 2048 + t;
    #pragma unroll
    for (int u = 0; u < 8; ++u) {
      int e = base + u * 256;
      if (e < E) rank[e] = atomicAdd(&cnt[dst[e]], 1);
    }
    return;
  }
  bid -= nb_hist;
  if (bid < nb_cvt) {
    int i = (bid * 256 + t) * 8;
    if (i >= nelem) return;
    float4 v0 = *(const float4*)(feat + i);
    float4 v1 = *(const float4*)(feat + i + 4);
    ushort4 a, b;
    a.x = f2bf(v0.x); a.y = f2bf(v0.y); a.z = f2bf(v0.z); a.w = f2bf(v0.w);
    b.x = f2bf(v1.x); b.y = f2bf(v1.y); b.z = f2bf(v1.z); b.w = f2bf(v1.w);
    *(ushort4*)(fb + i) = a;
    *(ushort4*)(fb + i + 4) = b;
  } else {
    int idx = (bid - nb_cvt) * 256 + t;   // covers NPAD*D_DIM exactly
    int n = idx >> 8, k = idx & 255;
    float v = 0.f;
    if (n < 256) v = W_lin[k * 256 + n];
    else if (n < 512) v = W_res[k * 256 + (n - 256)];
    else if (n < 520) {
      int h = n - 512; float s = 0.f;
      #pragma unroll
      for (int c = 0; c < 32; ++c) s += W_lin[k * 256 + h * 32 + c] * att_l[h * 32 + c];
      v = s;
    } else if (n < 528) {
      int h = n - 520; float s = 0.f;
      #pragma unroll
      for (int c = 0; c < 32; ++c) s += W_lin[k * 256 + h * 32 + c] * att_r[h * 32 + c];
      v = s;
    }
    Bt[idx] = f2bf(v);
  }
}

// ---------------- scans ----------------
__global__ __launch_bounds__(256) void scan_partial(const int* __restrict__ cnt,
                                                    int* __restrict__ bsum, int N) {
  __shared__ int s[256];
  int t = threadIdx.x;
  int i = blockIdx.x * 256 + t;
  s[t] = (i < N) ? cnt[i] : 0;
  __syncthreads();
  for (int off = 128; off > 0; off >>= 1) {
    if (t < off) s[t] += s[t + off];
    __syncthreads();
  }
  if (t == 0) bsum[blockIdx.x] = s[0];
}

__global__ __launch_bounds__(256) void scan_top(int* __restrict__ bsum, int nb) {
  __shared__ int s[256];
  int t = threadIdx.x;
  int v = (t < nb) ? bsum[t] : 0;
  s[t] = v;
  __syncthreads();
  for (int off = 1; off < 256; off <<= 1) {
    int u = (t >= off) ? s[t - off] : 0;
    __syncthreads();
    s[t] += u;
    __syncthreads();
  }
  if (t < nb) bsum[t] = s[t] - v;   // exclusive
}

__global__ __launch_bounds__(256) void scan_apply(const int* __restrict__ cnt,
                                                  const int* __restrict__ bsum,
                                                  int* __restrict__ row_ptr, int N) {
  __shared__ int s[256];
  int t = threadIdx.x;
  int i = blockIdx.x * 256 + t;
  int v = (i < N) ? cnt[i] : 0;
  s[t] = v;
  __syncthreads();
  for (int off = 1; off < 256; off <<= 1) {
    int u = (t >= off) ? s[t - off] : 0;
    __syncthreads();
    s[t] += u;
    __syncthreads();
  }
  int excl = bsum[blockIdx.x] + s[t] - v;
  if (i < N) {
    row_ptr[i] = excl;
    if (i == N - 1) row_ptr[N] = excl + v;
  }
}

// ---------------- bf16 MFMA GEMM (pure, BK=64, XOR-swizzled LDS) ----------------
// Swizzle discipline (rule #21): global_load_lds writes LINEARLY (base+lane*16),
// so the swizzle is applied by permuting the per-lane GLOBAL source column
// (koff ^ (row&7)) and applying the SAME involution on the ds_read column.
__global__ __launch_bounds__(256) void gemm_kernel(
    const unsigned short* __restrict__ A,   // feat bf16 [M][256]
    const unsigned short* __restrict__ Bt,  // [640][256]
    float* __restrict__ out, unsigned short* __restrict__ xbf,
    float* __restrict__ alpha_l, float* __restrict__ alpha_r, int M, int gx) {
  __shared__ unsigned short As[128 * 64];
  __shared__ unsigned short Bs[128 * 64];

  int tid  = threadIdx.x;
  int w    = tid >> 6, lane = tid & 63;
  int gb   = (int)blockIdx.x;
  int bm   = (gb % gx) * 128, bn = (gb / gx) * 128;
  int wm   = (w & 1) * 64, wn = (w >> 1) * 64;
  int l16  = lane & 15, quad = lane >> 4;

  f32x4 acc[4][4] = {};

  int sr8     = lane >> 3;                       // row within 8-row staging group
  int koff_sw = (((lane & 7) ^ sr8) * 8);        // pre-swizzled source column (elements)

  for (int k0 = 0; k0 < 256; k0 += 64) {
    #pragma unroll
    for (int j = 0; j < 4; ++j) {
      int rbase = w * 32 + j * 8;
      int rga = bm + rbase + sr8; if (rga > M - 1) rga = M - 1;   // clamp (stores guarded)
      gld16(A  + (size_t)rga * 256 + k0 + koff_sw, &As[rbase * 64]);
      gld16(Bt + (size_t)(bn + rbase + sr8) * 256 + k0 + koff_sw, &Bs[rbase * 64]);
    }
    __syncthreads();
    #pragma unroll
    for (int kk = 0; kk < 64; kk += 32) {
      bf16x8 a[4], b[4];
      #pragma unroll
      for (int mi = 0; mi < 4; ++mi) {
        int r = wm + mi * 16 + l16;
        int col = (kk * 2 + quad * 16) ^ ((r & 7) << 4);   // byte col, same involution
        a[mi] = *(const bf16x8*)((const char*)&As[r * 64] + col);
      }
      #pragma unroll
      for (int ni = 0; ni < 4; ++ni) {
        int r = wn + ni * 16 + l16;
        int col = (kk * 2 + quad * 16) ^ ((r & 7) << 4);
        b[ni] = *(const bf16x8*)((const char*)&Bs[r * 64] + col);
      }
      #pragma unroll
      for (int mi = 0; mi < 4; ++mi)
        #pragma unroll
        for (int ni = 0; ni < 4; ++ni)
          acc[mi][ni] = __builtin_amdgcn_mfma_f32_16x16x32_bf16(a[mi], b[ni], acc[mi][ni], 0, 0, 0);
    }
    __syncthreads();
  }

  #pragma unroll
  for (int mi = 0; mi < 4; ++mi) {
    #pragma unroll
    for (int r = 0; r < 4; ++r) {
      int row = bm + wm + mi * 16 + quad * 4 + r;
      if (row >= M) continue;
      #pragma unroll
      for (int ni = 0; ni < 4; ++ni) {
        int n = bn + wn + ni * 16 + l16;
        float v = acc[mi][ni][r];
        if (n < 256)      xbf[(size_t)row * 256 + n] = f2bf(v);
        else if (n < 512) out[(size_t)row * 256 + (n - 256)] = v;
        else if (n < 520) alpha_l[row * 8 + (n - 512)] = v;
        else if (n < 528) alpha_r[row * 8 + (n - 520)] = v;
      }
    }
  }
}

// ---------------- scatter (merged): rank-based placement + score precompute ----------------
// Round-2-verified form. Edge-parallel (latency-tolerant): gathers the two L2-resident
// 32 B alpha rows, computes leaky_relu + exp, writes srcA[pos] (4 B) + pexp[pos] (16 B).
// vs round-5's split (scatter + dstA fill + score): deletes two passes (~38 MB of stream
// traffic) and two launches at the cost of scattering 20 B instead of 8 B per edge.
__global__ __launch_bounds__(256) void scatter_kernel(
    const int* __restrict__ eidx, const float* __restrict__ ew,
    const int* __restrict__ row_ptr, const int* __restrict__ rank,
    const float* __restrict__ alpha_l, const float* __restrict__ alpha_r,
    int* __restrict__ srcA, unsigned short* __restrict__ pexp, int E) {
  int e = blockIdx.x * 256 + threadIdx.x;
  if (e >= E) return;
  int s = eidx[e], d = eidx[E + e];
  int pos = row_ptr[d] + rank[e];
  float w = ew[e];
  float4 al0 = *(const float4*)(alpha_l + (size_t)s * 8);
  float4 al1 = *(const float4*)(alpha_l + (size_t)s * 8 + 4);
  float4 ar0 = *(const float4*)(alpha_r + (size_t)d * 8);
  float4 ar1 = *(const float4*)(alpha_r + (size_t)d * 8 + 4);
  float a[8] = {al0.x + ar0.x, al0.y + ar0.y, al0.z + ar0.z, al0.w + ar0.w,
                al1.x + ar1.x, al1.y + ar1.y, al1.z + ar1.z, al1.w + ar1.w};
  unsigned short pb[8];
  #pragma unroll
  for (int h = 0; h < 8; ++h) {
    float v = w * a[h];
    v = (v > 0.f) ? v : 0.2f * v;        // leaky_relu(0.2)
    pb[h] = f2bf(__expf(v));             // softmax numerator (scores bounded, no max-shift)
  }
  ushort4 o0, o1;
  o0.x = pb[0]; o0.y = pb[1]; o0.z = pb[2]; o0.w = pb[3];
  o1.x = pb[4]; o1.y = pb[5]; o1.z = pb[6]; o1.w = pb[7];
  srcA[pos] = s;
  *(ushort4*)(pexp + (size_t)pos * 8) = o0;
  *(ushort4*)(pexp + (size_t)pos * 8 + 4) = o1;
}

// ---------------- agg: 2 waves per dst node, gather-free score path ----------------
// Round-5-verified form (116 us): loop reads srcA (stream), pexp (stream), xbf (the only
// gather). Score chain (alpha gather + exp) removed from the serial loop -> latency-bound
// chain is a single L2/L3 round trip per group.
__global__ __launch_bounds__(256) void agg_kernel(
    const int* __restrict__ row_ptr, const int* __restrict__ srcA,
    const unsigned short* __restrict__ pexp,
    const unsigned short* __restrict__ xbf, float* __restrict__ out, int N) {
  __shared__ float red[2][64][6];        // [node-in-block][lane][l,ac0..3] (+pad)
  int nin  = threadIdx.x >> 7;           // node within block
  int wv   = (threadIdx.x >> 6) & 1;     // wave within node
  int lane = threadIdx.x & 63;
  int node = blockIdx.x * 2 + nin;
  bool active = node < N;
  int h  = lane >> 3;                    // head for this lane's 4 channels
  int cb = lane << 2;                    // channel base (0..252)

  float l = 0.f, ac0 = 0.f, ac1 = 0.f, ac2 = 0.f, ac3 = 0.f;

  if (active) {
    int beg = row_ptr[node], end = row_ptr[node + 1];
    if (beg < end) {
      int last = end - 1;
      const unsigned short* xb = xbf + cb;
      for (int jg = beg + wv * 4; jg < end; jg += 8) {
        int s[4]; float pv[4];
        #pragma unroll
        for (int u = 0; u < 4; ++u) {
          int t = jg + u; t = (t < last) ? t : last;   // clamp (masked below)
          s[u]  = srcA[t];
          pv[u] = bf2f(pexp[(size_t)t * 8 + h]);
        }
        ushort4 xv[4];
        #pragma unroll
        for (int u = 0; u < 4; ++u)
          xv[u] = *(const ushort4*)(xb + ((size_t)s[u] << 8));
        #pragma unroll
        for (int u = 0; u < 4; ++u) {
          float p = (jg + u < end) ? pv[u] : 0.f;      // mask tail
          l += p;
          ac0 = fmaf(p, bf2f(xv[u].x), ac0);
          ac1 = fmaf(p, bf2f(xv[u].y), ac1);
          ac2 = fmaf(p, bf2f(xv[u].z), ac2);
          ac3 = fmaf(p, bf2f(xv[u].w), ac3);
        }
      }
    }
  }

  if (wv == 1) {
    red[nin][lane][0] = l;
    red[nin][lane][1] = ac0; red[nin][lane][2] = ac1;
    red[nin][lane][3] = ac2; red[nin][lane][4] = ac3;
  }
  __syncthreads();
  if (active && wv == 0) {
    l   += red[nin][lane][0];
    ac0 += red[nin][lane][1]; ac1 += red[nin][lane][2];
    ac2 += red[nin][lane][3]; ac3 += red[nin][lane][4];
    float r = 1.0f / (l + 1e-16f);
    float o0 = ac0 * r, o1 = ac1 * r, o2 = ac2 * r, o3 = ac3 * r;
    o0 = (o0 > 0.f) ? o0 : expm1f(o0);  // elu
    o1 = (o1 > 0.f) ? o1 : expm1f(o1);
    o2 = (o2 > 0.f) ? o2 : expm1f(o2);
    o3 = (o3 > 0.f) ? o3 : expm1f(o3);
    float4* op = (float4*)(out + ((size_t)node << 8) + cb);
    float4 res = *op;                    // residual written by gemm epilogue
    res.x += o0; res.y += o1; res.z += o2; res.w += o3;
    *op = res;
  }
}

extern "C" void kernel_launch(void* const* d_in, const int* in_sizes, int n_in,
                              void* d_out, int out_size, void* d_ws, size_t ws_size,
                              hipStream_t stream) {
  const float* feat  = (const float*)d_in[0];
  const float* ew    = (const float*)d_in[1];
  const float* W_lin = (const float*)d_in[2];
  const float* att_l = (const float*)d_in[3];
  const float* att_r = (const float*)d_in[4];
  const float* W_res = (const float*)d_in[5];
  const int*   eidx  = (const int*)d_in[6];
  float* out = (float*)d_out;

  int N = in_sizes[0] / D_DIM;
  int E = in_sizes[1];

  char* p = (char*)d_ws;
  auto alloc = [&](size_t bytes) {
    char* r = p; p += (bytes + 255) & ~(size_t)255; return r;
  };
  unsigned short* xbf  = (unsigned short*)alloc((size_t)N * 256 * 2);   // 25.6 MB
  unsigned short* fb   = (unsigned short*)alloc((size_t)N * 256 * 2);   // 25.6 MB
  float* alpha_l       = (float*)alloc((size_t)N * 8 * 4);
  float* alpha_r       = (float*)alloc((size_t)N * 8 * 4);
  unsigned short* Bt   = (unsigned short*)alloc((size_t)NPAD * D_DIM * 2);
  int*   row_ptr       = (int*)alloc((size_t)(N + 1) * 4);
  int*   cnt           = (int*)alloc((size_t)N * 4);
  int*   rank          = (int*)alloc((size_t)E * 4);
  int*   bsum          = (int*)alloc(1024);
  int*   srcA          = (int*)alloc((size_t)E * 4);                    // 6.4 MB
  unsigned short* pexp = (unsigned short*)alloc((size_t)E * 8 * 2);     // 25.6 MB

  // fallback: alias pexp onto fb (fb dead after gemm; scatter runs after gemm) -- exact fit
  if ((size_t)(p - (char*)d_ws) > ws_size) pexp = fb;

  int nb      = (N + 255) / 256;
  int nb_cvt  = (N * 256 / 8 + 255) / 256;
  int nb_prep = NPAD * D_DIM / 256;
  int nb_hist = (E + 2047) / 2048;    // 8 edges/thread
  int nb_scat = (E + 255) / 256;
  int gx = (N + 127) / 128;
  int gemm_blocks = gx * (NPAD / 128);

  hipMemsetAsync(cnt, 0, (size_t)N * 4, stream);

  setup_fused<<<nb_hist + nb_cvt + nb_prep, 256, 0, stream>>>(
      feat, fb, W_lin, W_res, att_l, att_r, Bt, N * 256, nb_hist, nb_cvt,
      eidx + E, cnt, rank, E);

  gemm_kernel<<<gemm_blocks, 256, 0, stream>>>(
      fb, Bt, out, xbf, alpha_l, alpha_r, N, gx);

  scan_partial<<<nb, 256, 0, stream>>>(cnt, bsum, N);
  scan_top<<<1, 256, 0, stream>>>(bsum, nb);
  scan_apply<<<nb, 256, 0, stream>>>(cnt, bsum, row_ptr, N);

  scatter_kernel<<<nb_scat, 256, 0, stream>>>(
      eidx, ew, row_ptr, rank, alpha_l, alpha_r, srcA, pexp, E);

  agg_kernel<<<(N + 1) / 2, 256, 0, stream>>>(row_ptr, srcA, pexp, xbf, out, N);
}

// Round 7
// 410.150 us; speedup vs baseline: 1.0871x; 1.0871x over previous
//
#include <hip/hip_runtime.h>
#include <stdint.h>

#define D_DIM 256
#define NPAD  640   // 256 (W_lin) + 256 (W_res) + 8 (att_l) + 8 (att_r) + 112 zero pad -> 5 x 128 tiles

typedef __bf16 bf16x8 __attribute__((ext_vector_type(8)));
typedef float  f32x4  __attribute__((ext_vector_type(4)));

__device__ __forceinline__ float bf2f(unsigned short u) {
  union { unsigned int i; float f; } cv; cv.i = ((unsigned int)u) << 16; return cv.f;
}
__device__ __forceinline__ unsigned short f2bf(float f) {
  union { float f; unsigned int i; } cv; cv.f = f;
  unsigned int i = cv.i;
  unsigned int lsb = (i >> 16) & 1u;
  i += 0x7fffu + lsb;   // round-to-nearest-even
  return (unsigned short)(i >> 16);
}
__device__ __forceinline__ void gld16(const void* gptr, void* lptr) {
  __builtin_amdgcn_global_load_lds(
      (const __attribute__((address_space(1))) unsigned int*)gptr,
      (__attribute__((address_space(3))) unsigned int*)lptr, 16, 0, 0);
}

// ---------------- setup: [cvt_feat | prep_bt] by block range ----------------
__global__ __launch_bounds__(256) void setup_cvt_prep(
    const float* __restrict__ feat, unsigned short* __restrict__ fb,
    const float* __restrict__ W_lin, const float* __restrict__ W_res,
    const float* __restrict__ att_l, const float* __restrict__ att_r,
    unsigned short* __restrict__ Bt, int nelem, int nb_cvt) {
  int bid = blockIdx.x, t = threadIdx.x;
  if (bid < nb_cvt) {
    int i = (bid * 256 + t) * 8;
    if (i >= nelem) return;
    float4 v0 = *(const float4*)(feat + i);
    float4 v1 = *(const float4*)(feat + i + 4);
    ushort4 a, b;
    a.x = f2bf(v0.x); a.y = f2bf(v0.y); a.z = f2bf(v0.z); a.w = f2bf(v0.w);
    b.x = f2bf(v1.x); b.y = f2bf(v1.y); b.z = f2bf(v1.z); b.w = f2bf(v1.w);
    *(ushort4*)(fb + i) = a;
    *(ushort4*)(fb + i + 4) = b;
  } else {
    int idx = (bid - nb_cvt) * 256 + t;   // covers NPAD*D_DIM exactly
    int n = idx >> 8, k = idx & 255;
    float v = 0.f;
    if (n < 256) v = W_lin[k * 256 + n];
    else if (n < 512) v = W_res[k * 256 + (n - 256)];
    else if (n < 520) {
      int h = n - 512; float s = 0.f;
      #pragma unroll
      for (int c = 0; c < 32; ++c) s += W_lin[k * 256 + h * 32 + c] * att_l[h * 32 + c];
      v = s;
    } else if (n < 528) {
      int h = n - 520; float s = 0.f;
      #pragma unroll
      for (int c = 0; c < 32; ++c) s += W_lin[k * 256 + h * 32 + c] * att_r[h * 32 + c];
      v = s;
    }
    Bt[idx] = f2bf(v);
  }
}

// ---------------- standalone histogram ----------------
__global__ __launch_bounds__(256) void hist_kernel(
    const int* __restrict__ dst, int* __restrict__ cnt, int* __restrict__ rank, int E) {
  int base = (int)blockIdx.x * 2048 + threadIdx.x;
  #pragma unroll
  for (int u = 0; u < 8; ++u) {
    int e = base + u * 256;
    if (e < E) rank[e] = atomicAdd(&cnt[dst[e]], 1);   // 8 independent RMWs in flight
  }
}

// ---------------- scans ----------------
__global__ __launch_bounds__(256) void scan_partial(const int* __restrict__ cnt,
                                                    int* __restrict__ bsum, int N) {
  __shared__ int s[256];
  int t = threadIdx.x;
  int i = blockIdx.x * 256 + t;
  s[t] = (i < N) ? cnt[i] : 0;
  __syncthreads();
  for (int off = 128; off > 0; off >>= 1) {
    if (t < off) s[t] += s[t + off];
    __syncthreads();
  }
  if (t == 0) bsum[blockIdx.x] = s[0];
}

__global__ __launch_bounds__(256) void scan_top(int* __restrict__ bsum, int nb) {
  __shared__ int s[256];
  int t = threadIdx.x;
  int v = (t < nb) ? bsum[t] : 0;
  s[t] = v;
  __syncthreads();
  for (int off = 1; off < 256; off <<= 1) {
    int u = (t >= off) ? s[t - off] : 0;
    __syncthreads();
    s[t] += u;
    __syncthreads();
  }
  if (t < nb) bsum[t] = s[t] - v;   // exclusive
}

__global__ __launch_bounds__(256) void scan_apply(const int* __restrict__ cnt,
                                                  const int* __restrict__ bsum,
                                                  int* __restrict__ row_ptr, int N) {
  __shared__ int s[256];
  int t = threadIdx.x;
  int i = blockIdx.x * 256 + t;
  int v = (i < N) ? cnt[i] : 0;
  s[t] = v;
  __syncthreads();
  for (int off = 1; off < 256; off <<= 1) {
    int u = (t >= off) ? s[t - off] : 0;
    __syncthreads();
    s[t] += u;
    __syncthreads();
  }
  int excl = bsum[blockIdx.x] + s[t] - v;
  if (i < N) {
    row_ptr[i] = excl;
    if (i == N - 1) row_ptr[N] = excl + v;
  }
}

// ---------------- bf16 MFMA GEMM (BK=64, XOR-swizzled LDS, bm-major + XCD chunk) ----------------
// Block mapping v2. Old bn-major mapping swept all 391 bm-tiles per bn-tile: A (25.6 MB)
// was TCC-filled 5x (128 MB) and round-robin XCD dispatch put even co-A-tile blocks on
// different per-XCD L2s. Now: (1) bijective XCD-chunk swizzle (m204 formula; nwg%8!=0)
// gives each XCD a CONTIGUOUS range of work; (2) bm-major order within that range makes
// the 5 bn-tiles of one A-tile consecutive on the SAME XCD -> A-tile L2-hits after the
// first, Bt (327 KB) L2-resident. Expected fill ~256 MB -> ~30 MB.
__global__ __launch_bounds__(256) void gemm_kernel(
    const unsigned short* __restrict__ A,   // feat bf16 [M][256]
    const unsigned short* __restrict__ Bt,  // [640][256]
    float* __restrict__ out, unsigned short* __restrict__ xbf,
    float* __restrict__ alpha_l, float* __restrict__ alpha_r, int M, int gx) {
  __shared__ unsigned short As[128 * 64];
  __shared__ unsigned short Bs[128 * 64];

  int tid  = threadIdx.x;
  int w    = tid >> 6, lane = tid & 63;

  // bijective XCD-chunk swizzle (consecutive blockIdx -> consecutive XCDs on MI355X)
  int nwg  = (int)gridDim.x;
  int q    = nwg >> 3, r = nwg & 7;
  int xcd  = (int)blockIdx.x & 7, j = (int)blockIdx.x >> 3;
  int wg   = (xcd < r ? xcd * (q + 1) : r * (q + 1) + (xcd - r) * q) + j;

  int nbn  = NPAD / 128;                   // 5
  int bm   = (wg / nbn) * 128, bn = (wg % nbn) * 128;   // bm-major: A-tile reuse
  int wm   = (w & 1) * 64, wn = (w >> 1) * 64;
  int l16  = lane & 15, quad = lane >> 4;

  f32x4 acc[4][4] = {};

  int sr8     = lane >> 3;                       // row within 8-row staging group
  int koff_sw = (((lane & 7) ^ sr8) * 8);        // pre-swizzled source column (elements)

  for (int k0 = 0; k0 < 256; k0 += 64) {
    #pragma unroll
    for (int jj = 0; jj < 4; ++jj) {
      int rbase = w * 32 + jj * 8;
      int rga = bm + rbase + sr8; if (rga > M - 1) rga = M - 1;   // clamp (stores guarded)
      gld16(A  + (size_t)rga * 256 + k0 + koff_sw, &As[rbase * 64]);
      gld16(Bt + (size_t)(bn + rbase + sr8) * 256 + k0 + koff_sw, &Bs[rbase * 64]);
    }
    __syncthreads();
    #pragma unroll
    for (int kk = 0; kk < 64; kk += 32) {
      bf16x8 a[4], b[4];
      #pragma unroll
      for (int mi = 0; mi < 4; ++mi) {
        int rr = wm + mi * 16 + l16;
        int col = (kk * 2 + quad * 16) ^ ((rr & 7) << 4);   // byte col, same involution
        a[mi] = *(const bf16x8*)((const char*)&As[rr * 64] + col);
      }
      #pragma unroll
      for (int ni = 0; ni < 4; ++ni) {
        int rr = wn + ni * 16 + l16;
        int col = (kk * 2 + quad * 16) ^ ((rr & 7) << 4);
        b[ni] = *(const bf16x8*)((const char*)&Bs[rr * 64] + col);
      }
      #pragma unroll
      for (int mi = 0; mi < 4; ++mi)
        #pragma unroll
        for (int ni = 0; ni < 4; ++ni)
          acc[mi][ni] = __builtin_amdgcn_mfma_f32_16x16x32_bf16(a[mi], b[ni], acc[mi][ni], 0, 0, 0);
    }
    __syncthreads();
  }

  #pragma unroll
  for (int mi = 0; mi < 4; ++mi) {
    #pragma unroll
    for (int rr = 0; rr < 4; ++rr) {
      int row = bm + wm + mi * 16 + quad * 4 + rr;
      if (row >= M) continue;
      #pragma unroll
      for (int ni = 0; ni < 4; ++ni) {
        int n = bn + wn + ni * 16 + l16;
        float v = acc[mi][ni][rr];
        if (n < 256)      xbf[(size_t)row * 256 + n] = f2bf(v);
        else if (n < 512) out[(size_t)row * 256 + (n - 256)] = v;
        else if (n < 520) alpha_l[row * 8 + (n - 512)] = v;
        else if (n < 528) alpha_r[row * 8 + (n - 520)] = v;
      }
    }
  }
}

// ---------------- scatter (atomic-free, rank-based) — cheap 8 B/edge payload ----------------
// Proven (R2/R6, twice): anything heavier scattered per-edge (pexp 16 B + srcA) costs more
// in this kernel than it saves in agg. Keep the scattered payload at 8 B.
__global__ __launch_bounds__(256) void scatter_kernel(
    const int* __restrict__ eidx, const float* __restrict__ ew,
    const int* __restrict__ row_ptr, const int* __restrict__ rank,
    int2* __restrict__ pairs, int E) {
  int e = blockIdx.x * 256 + threadIdx.x;
  if (e < E) {
    int d = eidx[E + e];
    int pos = row_ptr[d] + rank[e];
    int2 p; p.x = eidx[e]; p.y = __float_as_int(ew[e]);
    pairs[pos] = p;
  }
}

// ---------------- agg: 2 waves per dst node, alpha+exp in-loop (R3 form, 139 us) ----------------
// pexp-precompute variants make agg 116 us but their production costs +34..+60 us (R5/R6)
// -> net loss. The in-loop form's extra chain (alpha_l gather + exp) costs +23 us here and
// zero elsewhere.
__global__ __launch_bounds__(256) void agg_kernel(
    const int* __restrict__ row_ptr, const int2* __restrict__ pairs,
    const float* __restrict__ alpha_l, const float* __restrict__ alpha_r,
    const unsigned short* __restrict__ xbf, float* __restrict__ out, int N) {
  __shared__ float red[2][64][6];        // [node-in-block][lane][l,ac0..3] (+pad)
  int nin  = threadIdx.x >> 7;           // node within block
  int wv   = (threadIdx.x >> 6) & 1;     // wave within node
  int lane = threadIdx.x & 63;
  int node = blockIdx.x * 2 + nin;
  bool active = node < N;
  int h  = lane >> 3;                    // head for this lane's 4 channels
  int cb = lane << 2;                    // channel base (0..252)

  float l = 0.f, ac0 = 0.f, ac1 = 0.f, ac2 = 0.f, ac3 = 0.f;

  if (active) {
    int beg = row_ptr[node], end = row_ptr[node + 1];
    if (beg < end) {
      float arv = alpha_r[node * 8 + h];
      int last = end - 1;
      const unsigned short* xb = xbf + cb;
      for (int jg = beg + wv * 4; jg < end; jg += 8) {
        int2 q[4];
        #pragma unroll
        for (int u = 0; u < 4; ++u) {
          int t = jg + u; t = (t < last) ? t : last;   // clamp (masked below)
          q[u] = pairs[t];
        }
        float al[4];
        #pragma unroll
        for (int u = 0; u < 4; ++u) al[u] = alpha_l[(size_t)q[u].x * 8 + h];
        ushort4 xv[4];
        #pragma unroll
        for (int u = 0; u < 4; ++u)
          xv[u] = *(const ushort4*)(xb + ((size_t)q[u].x << 8));
        #pragma unroll
        for (int u = 0; u < 4; ++u) {
          float a = __int_as_float(q[u].y) * (al[u] + arv);
          a = (a > 0.f) ? a : 0.2f * a;            // leaky_relu(0.2)
          float p = __expf(a);
          p = (jg + u < end) ? p : 0.f;            // mask tail
          l += p;
          ac0 = fmaf(p, bf2f(xv[u].x), ac0);
          ac1 = fmaf(p, bf2f(xv[u].y), ac1);
          ac2 = fmaf(p, bf2f(xv[u].z), ac2);
          ac3 = fmaf(p, bf2f(xv[u].w), ac3);
        }
      }
    }
  }

  if (wv == 1) {
    red[nin][lane][0] = l;
    red[nin][lane][1] = ac0; red[nin][lane][2] = ac1;
    red[nin][lane][3] = ac2; red[nin][lane][4] = ac3;
  }
  __syncthreads();
  if (active && wv == 0) {
    l   += red[nin][lane][0];
    ac0 += red[nin][lane][1]; ac1 += red[nin][lane][2];
    ac2 += red[nin][lane][3]; ac3 += red[nin][lane][4];
    float r = 1.0f / (l + 1e-16f);
    float o0 = ac0 * r, o1 = ac1 * r, o2 = ac2 * r, o3 = ac3 * r;
    o0 = (o0 > 0.f) ? o0 : expm1f(o0);  // elu
    o1 = (o1 > 0.f) ? o1 : expm1f(o1);
    o2 = (o2 > 0.f) ? o2 : expm1f(o2);
    o3 = (o3 > 0.f) ? o3 : expm1f(o3);
    float4* op = (float4*)(out + ((size_t)node << 8) + cb);
    float4 res = *op;                    // residual written by gemm epilogue
    res.x += o0; res.y += o1; res.z += o2; res.w += o3;
    *op = res;
  }
}

extern "C" void kernel_launch(void* const* d_in, const int* in_sizes, int n_in,
                              void* d_out, int out_size, void* d_ws, size_t ws_size,
                              hipStream_t stream) {
  const float* feat  = (const float*)d_in[0];
  const float* ew    = (const float*)d_in[1];
  const float* W_lin = (const float*)d_in[2];
  const float* att_l = (const float*)d_in[3];
  const float* att_r = (const float*)d_in[4];
  const float* W_res = (const float*)d_in[5];
  const int*   eidx  = (const int*)d_in[6];
  float* out = (float*)d_out;

  int N = in_sizes[0] / D_DIM;
  int E = in_sizes[1];

  char* p = (char*)d_ws;
  auto alloc = [&](size_t bytes) {
    char* r = p; p += (bytes + 255) & ~(size_t)255; return r;
  };
  unsigned short* xbf  = (unsigned short*)alloc((size_t)N * 256 * 2);   // 25.6 MB
  unsigned short* fb   = (unsigned short*)alloc((size_t)N * 256 * 2);   // 25.6 MB
  float* alpha_l       = (float*)alloc((size_t)N * 8 * 4);
  float* alpha_r       = (float*)alloc((size_t)N * 8 * 4);
  unsigned short* Bt   = (unsigned short*)alloc((size_t)NPAD * D_DIM * 2);
  int*   row_ptr       = (int*)alloc((size_t)(N + 1) * 4);
  int*   cnt           = (int*)alloc((size_t)N * 4);
  int*   rank          = (int*)alloc((size_t)E * 4);
  int*   bsum          = (int*)alloc(1024);
  int2*  pairs_sep     = (int2*)alloc((size_t)E * 8);                   // 12.8 MB
  bool sep_ok = ((size_t)((char*)(pairs_sep + E) - (char*)d_ws) <= ws_size);
  // fallback: alias pairs onto fb (dead after gemm; scatter runs after gemm)
  int2* pairs = sep_ok ? pairs_sep : (int2*)fb;

  int nb      = (N + 255) / 256;
  int nb_cvt  = (N * 256 / 8 + 255) / 256;
  int nb_prep = NPAD * D_DIM / 256;
  int nb_hist = (E + 2047) / 2048;    // 8 edges/thread
  int nb_scat = (E + 255) / 256;
  int gx = (N + 127) / 128;
  int gemm_blocks = gx * (NPAD / 128);

  hipMemsetAsync(cnt, 0, (size_t)N * 4, stream);

  setup_cvt_prep<<<nb_cvt + nb_prep, 256, 0, stream>>>(
      feat, fb, W_lin, W_res, att_l, att_r, Bt, N * 256, nb_cvt);

  hist_kernel<<<nb_hist, 256, 0, stream>>>(eidx + E, cnt, rank, E);

  gemm_kernel<<<gemm_blocks, 256, 0, stream>>>(
      fb, Bt, out, xbf, alpha_l, alpha_r, N, gx);

  scan_partial<<<nb, 256, 0, stream>>>(cnt, bsum, N);
  scan_top<<<1, 256, 0, stream>>>(bsum, nb);
  scan_apply<<<nb, 256, 0, stream>>>(cnt, bsum, row_ptr, N);

  scatter_kernel<<<nb_scat, 256, 0, stream>>>(eidx, ew, row_ptr, rank, pairs, E);

  agg_kernel<<<(N + 1) / 2, 256, 0, stream>>>(row_ptr, pairs, alpha_l, alpha_r, xbf, out, N);
}

// Round 8
// 404.965 us; speedup vs baseline: 1.1010x; 1.0128x over previous
//
#include <hip/hip_runtime.h>
#include <stdint.h>

#define D_DIM 256
#define NPAD  640   // 256 (W_lin) + 256 (W_res) + 8 (att_l) + 8 (att_r) + 112 zero pad -> 5 x 128 tiles

typedef __bf16 bf16x8 __attribute__((ext_vector_type(8)));
typedef float  f32x4  __attribute__((ext_vector_type(4)));

__device__ __forceinline__ float bf2f(unsigned short u) {
  union { unsigned int i; float f; } cv; cv.i = ((unsigned int)u) << 16; return cv.f;
}
__device__ __forceinline__ unsigned short f2bf(float f) {
  union { float f; unsigned int i; } cv; cv.f = f;
  unsigned int i = cv.i;
  unsigned int lsb = (i >> 16) & 1u;
  i += 0x7fffu + lsb;   // round-to-nearest-even
  return (unsigned short)(i >> 16);
}
__device__ __forceinline__ void gld16(const void* gptr, void* lptr) {
  __builtin_amdgcn_global_load_lds(
      (const __attribute__((address_space(1))) unsigned int*)gptr,
      (__attribute__((address_space(3))) unsigned int*)lptr, 16, 0, 0);
}

// ---------------- fused setup: [hist | cvt_feat | prep_bt] by block range ----------------
// hist blocks FIRST (atomic-latency-bound, overlaps under the streaming cvt/prep blocks).
// No LDS anywhere here, so the R2 fusion failure (hist gating an LDS-heavy GEMM) does not
// apply. R6 decomposition: this fusion is worth ~-14 us vs split launches.
__global__ __launch_bounds__(256) void setup_fused(
    const float* __restrict__ feat, unsigned short* __restrict__ fb,
    const float* __restrict__ W_lin, const float* __restrict__ W_res,
    const float* __restrict__ att_l, const float* __restrict__ att_r,
    unsigned short* __restrict__ Bt, int nelem, int nb_hist, int nb_cvt,
    const int* __restrict__ dst, int* __restrict__ cnt, int* __restrict__ rank, int E) {
  int bid = blockIdx.x, t = threadIdx.x;
  if (bid < nb_hist) {
    int base = bid * 2048 + t;
    #pragma unroll
    for (int u = 0; u < 8; ++u) {
      int e = base + u * 256;
      if (e < E) rank[e] = atomicAdd(&cnt[dst[e]], 1);   // 8 independent RMWs in flight
    }
    return;
  }
  bid -= nb_hist;
  if (bid < nb_cvt) {
    int i = (bid * 256 + t) * 8;
    if (i >= nelem) return;
    float4 v0 = *(const float4*)(feat + i);
    float4 v1 = *(const float4*)(feat + i + 4);
    ushort4 a, b;
    a.x = f2bf(v0.x); a.y = f2bf(v0.y); a.z = f2bf(v0.z); a.w = f2bf(v0.w);
    b.x = f2bf(v1.x); b.y = f2bf(v1.y); b.z = f2bf(v1.z); b.w = f2bf(v1.w);
    *(ushort4*)(fb + i) = a;
    *(ushort4*)(fb + i + 4) = b;
  } else {
    int idx = (bid - nb_cvt) * 256 + t;   // covers NPAD*D_DIM exactly
    int n = idx >> 8, k = idx & 255;
    float v = 0.f;
    if (n < 256) v = W_lin[k * 256 + n];
    else if (n < 512) v = W_res[k * 256 + (n - 256)];
    else if (n < 520) {
      int h = n - 512; float s = 0.f;
      #pragma unroll
      for (int c = 0; c < 32; ++c) s += W_lin[k * 256 + h * 32 + c] * att_l[h * 32 + c];
      v = s;
    } else if (n < 528) {
      int h = n - 520; float s = 0.f;
      #pragma unroll
      for (int c = 0; c < 32; ++c) s += W_lin[k * 256 + h * 32 + c] * att_r[h * 32 + c];
      v = s;
    }
    Bt[idx] = f2bf(v);
  }
}

// ---------------- scans (2 launches: partial sums, then apply with folded top scan) ----------------
__global__ __launch_bounds__(256) void scan_partial(const int* __restrict__ cnt,
                                                    int* __restrict__ bsum, int N) {
  __shared__ int s[256];
  int t = threadIdx.x;
  int i = blockIdx.x * 256 + t;
  s[t] = (i < N) ? cnt[i] : 0;
  __syncthreads();
  for (int off = 128; off > 0; off >>= 1) {
    if (t < off) s[t] += s[t + off];
    __syncthreads();
  }
  if (t == 0) bsum[blockIdx.x] = s[0];
}

// scan_apply v3: folds the top-level scan in. Each block strided-sums bsum[0..b) (<=1
// element per thread at nb=196) + LDS reduce -> exclusive base; then the usual intra-block
// scan of cnt. Deletes the scan_top launch.
__global__ __launch_bounds__(256) void scan_apply(const int* __restrict__ cnt,
                                                  const int* __restrict__ bsum,
                                                  int* __restrict__ row_ptr, int N) {
  __shared__ int red[256];
  __shared__ int s[256];
  int t = threadIdx.x;
  int b = blockIdx.x;
  int acc = 0;
  for (int j = t; j < b; j += 256) acc += bsum[j];
  red[t] = acc;
  __syncthreads();
  for (int off = 128; off > 0; off >>= 1) {
    if (t < off) red[t] += red[t + off];
    __syncthreads();
  }
  int base = red[0];

  int i = b * 256 + t;
  int v = (i < N) ? cnt[i] : 0;
  s[t] = v;
  __syncthreads();
  for (int off = 1; off < 256; off <<= 1) {
    int u = (t >= off) ? s[t - off] : 0;
    __syncthreads();
    s[t] += u;
    __syncthreads();
  }
  int excl = base + s[t] - v;
  if (i < N) {
    row_ptr[i] = excl;
    if (i == N - 1) row_ptr[N] = excl + v;
  }
}

// ---------------- bf16 MFMA GEMM (BK=64, XOR-swizzled LDS, bm-major + XCD chunk) ----------------
// Unchanged from R7 (mapping change was neutral but harmless; kept to avoid churn).
__global__ __launch_bounds__(256) void gemm_kernel(
    const unsigned short* __restrict__ A,   // feat bf16 [M][256]
    const unsigned short* __restrict__ Bt,  // [640][256]
    float* __restrict__ out, unsigned short* __restrict__ xbf,
    float* __restrict__ alpha_l, float* __restrict__ alpha_r, int M, int gx) {
  __shared__ unsigned short As[128 * 64];
  __shared__ unsigned short Bs[128 * 64];

  int tid  = threadIdx.x;
  int w    = tid >> 6, lane = tid & 63;

  // bijective XCD-chunk swizzle (consecutive blockIdx -> consecutive XCDs on MI355X)
  int nwg  = (int)gridDim.x;
  int q    = nwg >> 3, r = nwg & 7;
  int xcd  = (int)blockIdx.x & 7, j = (int)blockIdx.x >> 3;
  int wg   = (xcd < r ? xcd * (q + 1) : r * (q + 1) + (xcd - r) * q) + j;

  int nbn  = NPAD / 128;                   // 5
  int bm   = (wg / nbn) * 128, bn = (wg % nbn) * 128;   // bm-major: A-tile reuse
  int wm   = (w & 1) * 64, wn = (w >> 1) * 64;
  int l16  = lane & 15, quad = lane >> 4;

  f32x4 acc[4][4] = {};

  int sr8     = lane >> 3;                       // row within 8-row staging group
  int koff_sw = (((lane & 7) ^ sr8) * 8);        // pre-swizzled source column (elements)

  for (int k0 = 0; k0 < 256; k0 += 64) {
    #pragma unroll
    for (int jj = 0; jj < 4; ++jj) {
      int rbase = w * 32 + jj * 8;
      int rga = bm + rbase + sr8; if (rga > M - 1) rga = M - 1;   // clamp (stores guarded)
      gld16(A  + (size_t)rga * 256 + k0 + koff_sw, &As[rbase * 64]);
      gld16(Bt + (size_t)(bn + rbase + sr8) * 256 + k0 + koff_sw, &Bs[rbase * 64]);
    }
    __syncthreads();
    #pragma unroll
    for (int kk = 0; kk < 64; kk += 32) {
      bf16x8 a[4], b[4];
      #pragma unroll
      for (int mi = 0; mi < 4; ++mi) {
        int rr = wm + mi * 16 + l16;
        int col = (kk * 2 + quad * 16) ^ ((rr & 7) << 4);   // byte col, same involution
        a[mi] = *(const bf16x8*)((const char*)&As[rr * 64] + col);
      }
      #pragma unroll
      for (int ni = 0; ni < 4; ++ni) {
        int rr = wn + ni * 16 + l16;
        int col = (kk * 2 + quad * 16) ^ ((rr & 7) << 4);
        b[ni] = *(const bf16x8*)((const char*)&Bs[rr * 64] + col);
      }
      #pragma unroll
      for (int mi = 0; mi < 4; ++mi)
        #pragma unroll
        for (int ni = 0; ni < 4; ++ni)
          acc[mi][ni] = __builtin_amdgcn_mfma_f32_16x16x32_bf16(a[mi], b[ni], acc[mi][ni], 0, 0, 0);
    }
    __syncthreads();
  }

  #pragma unroll
  for (int mi = 0; mi < 4; ++mi) {
    #pragma unroll
    for (int rr = 0; rr < 4; ++rr) {
      int row = bm + wm + mi * 16 + quad * 4 + rr;
      if (row >= M) continue;
      #pragma unroll
      for (int ni = 0; ni < 4; ++ni) {
        int n = bn + wn + ni * 16 + l16;
        float v = acc[mi][ni][rr];
        if (n < 256)      xbf[(size_t)row * 256 + n] = f2bf(v);
        else if (n < 512) out[(size_t)row * 256 + (n - 256)] = v;
        else if (n < 520) alpha_l[row * 8 + (n - 512)] = v;
        else if (n < 528) alpha_r[row * 8 + (n - 520)] = v;
      }
    }
  }
}

// ---------------- scatter (atomic-free, rank-based) — cheap 8 B/edge payload ----------------
// Proven twice (R2/R6): heavier scattered payloads (pexp) cost more here than they save in agg.
__global__ __launch_bounds__(256) void scatter_kernel(
    const int* __restrict__ eidx, const float* __restrict__ ew,
    const int* __restrict__ row_ptr, const int* __restrict__ rank,
    int2* __restrict__ pairs, int E) {
  int e = blockIdx.x * 256 + threadIdx.x;
  if (e < E) {
    int d = eidx[E + e];
    int pos = row_ptr[d] + rank[e];
    int2 p; p.x = eidx[e]; p.y = __float_as_int(ew[e]);
    pairs[pos] = p;
  }
}

// ---------------- agg: 2 waves per dst node, alpha+exp in-loop (R3 form) ----------------
// R8: node_base param -> launched as TWO half-grids. Diagnostic: drops agg's per-dispatch
// time to ~70 us so the production kernels (gemm, scatter, setup) surface in the top-5
// profile table for the first time. Arithmetic identical.
__global__ __launch_bounds__(256) void agg_kernel(
    const int* __restrict__ row_ptr, const int2* __restrict__ pairs,
    const float* __restrict__ alpha_l, const float* __restrict__ alpha_r,
    const unsigned short* __restrict__ xbf, float* __restrict__ out,
    int node_base, int node_lim) {
  __shared__ float red[2][64][6];        // [node-in-block][lane][l,ac0..3] (+pad)
  int nin  = threadIdx.x >> 7;           // node within block
  int wv   = (threadIdx.x >> 6) & 1;     // wave within node
  int lane = threadIdx.x & 63;
  int node = node_base + blockIdx.x * 2 + nin;
  bool active = node < node_lim;
  int h  = lane >> 3;                    // head for this lane's 4 channels
  int cb = lane << 2;                    // channel base (0..252)

  float l = 0.f, ac0 = 0.f, ac1 = 0.f, ac2 = 0.f, ac3 = 0.f;

  if (active) {
    int beg = row_ptr[node], end = row_ptr[node + 1];
    if (beg < end) {
      float arv = alpha_r[node * 8 + h];
      int last = end - 1;
      const unsigned short* xb = xbf + cb;
      for (int jg = beg + wv * 4; jg < end; jg += 8) {
        int2 q[4];
        #pragma unroll
        for (int u = 0; u < 4; ++u) {
          int t = jg + u; t = (t < last) ? t : last;   // clamp (masked below)
          q[u] = pairs[t];
        }
        float al[4];
        #pragma unroll
        for (int u = 0; u < 4; ++u) al[u] = alpha_l[(size_t)q[u].x * 8 + h];
        ushort4 xv[4];
        #pragma unroll
        for (int u = 0; u < 4; ++u)
          xv[u] = *(const ushort4*)(xb + ((size_t)q[u].x << 8));
        #pragma unroll
        for (int u = 0; u < 4; ++u) {
          float a = __int_as_float(q[u].y) * (al[u] + arv);
          a = (a > 0.f) ? a : 0.2f * a;            // leaky_relu(0.2)
          float p = __expf(a);
          p = (jg + u < end) ? p : 0.f;            // mask tail
          l += p;
          ac0 = fmaf(p, bf2f(xv[u].x), ac0);
          ac1 = fmaf(p, bf2f(xv[u].y), ac1);
          ac2 = fmaf(p, bf2f(xv[u].z), ac2);
          ac3 = fmaf(p, bf2f(xv[u].w), ac3);
        }
      }
    }
  }

  if (wv == 1) {
    red[nin][lane][0] = l;
    red[nin][lane][1] = ac0; red[nin][lane][2] = ac1;
    red[nin][lane][3] = ac2; red[nin][lane][4] = ac3;
  }
  __syncthreads();
  if (active && wv == 0) {
    l   += red[nin][lane][0];
    ac0 += red[nin][lane][1]; ac1 += red[nin][lane][2];
    ac2 += red[nin][lane][3]; ac3 += red[nin][lane][4];
    float r = 1.0f / (l + 1e-16f);
    float o0 = ac0 * r, o1 = ac1 * r, o2 = ac2 * r, o3 = ac3 * r;
    o0 = (o0 > 0.f) ? o0 : expm1f(o0);  // elu
    o1 = (o1 > 0.f) ? o1 : expm1f(o1);
    o2 = (o2 > 0.f) ? o2 : expm1f(o2);
    o3 = (o3 > 0.f) ? o3 : expm1f(o3);
    float4* op = (float4*)(out + ((size_t)node << 8) + cb);
    float4 res = *op;                    // residual written by gemm epilogue
    res.x += o0; res.y += o1; res.z += o2; res.w += o3;
    *op = res;
  }
}

extern "C" void kernel_launch(void* const* d_in, const int* in_sizes, int n_in,
                              void* d_out, int out_size, void* d_ws, size_t ws_size,
                              hipStream_t stream) {
  const float* feat  = (const float*)d_in[0];
  const float* ew    = (const float*)d_in[1];
  const float* W_lin = (const float*)d_in[2];
  const float* att_l = (const float*)d_in[3];
  const float* att_r = (const float*)d_in[4];
  const float* W_res = (const float*)d_in[5];
  const int*   eidx  = (const int*)d_in[6];
  float* out = (float*)d_out;

  int N = in_sizes[0] / D_DIM;
  int E = in_sizes[1];

  char* p = (char*)d_ws;
  auto alloc = [&](size_t bytes) {
    char* r = p; p += (bytes + 255) & ~(size_t)255; return r;
  };
  unsigned short* xbf  = (unsigned short*)alloc((size_t)N * 256 * 2);   // 25.6 MB
  unsigned short* fb   = (unsigned short*)alloc((size_t)N * 256 * 2);   // 25.6 MB
  float* alpha_l       = (float*)alloc((size_t)N * 8 * 4);
  float* alpha_r       = (float*)alloc((size_t)N * 8 * 4);
  unsigned short* Bt   = (unsigned short*)alloc((size_t)NPAD * D_DIM * 2);
  int*   row_ptr       = (int*)alloc((size_t)(N + 1) * 4);
  int*   cnt           = (int*)alloc((size_t)N * 4);
  int*   rank          = (int*)alloc((size_t)E * 4);
  int*   bsum          = (int*)alloc(1024);
  int2*  pairs_sep     = (int2*)alloc((size_t)E * 8);                   // 12.8 MB
  bool sep_ok = ((size_t)((char*)(pairs_sep + E) - (char*)d_ws) <= ws_size);
  // fallback: alias pairs onto fb (dead after gemm; scatter runs after gemm)
  int2* pairs = sep_ok ? pairs_sep : (int2*)fb;

  int nb      = (N + 255) / 256;
  int nb_cvt  = (N * 256 / 8 + 255) / 256;
  int nb_prep = NPAD * D_DIM / 256;
  int nb_hist = (E + 2047) / 2048;    // 8 edges/thread
  int nb_scat = (E + 255) / 256;
  int gx = (N + 127) / 128;
  int gemm_blocks = gx * (NPAD / 128);

  hipMemsetAsync(cnt, 0, (size_t)N * 4, stream);

  setup_fused<<<nb_hist + nb_cvt + nb_prep, 256, 0, stream>>>(
      feat, fb, W_lin, W_res, att_l, att_r, Bt, N * 256, nb_hist, nb_cvt,
      eidx + E, cnt, rank, E);

  gemm_kernel<<<gemm_blocks, 256, 0, stream>>>(
      fb, Bt, out, xbf, alpha_l, alpha_r, N, gx);

  scan_partial<<<nb, 256, 0, stream>>>(cnt, bsum, N);
  scan_apply<<<nb, 256, 0, stream>>>(cnt, bsum, row_ptr, N);

  scatter_kernel<<<nb_scat, 256, 0, stream>>>(eidx, ew, row_ptr, rank, pairs, E);

  // agg split into two half-grids (diagnostic: surfaces production kernels in top-5)
  int Nh = ((N / 2) + 1) & ~1;            // even split point
  if (Nh > N) Nh = N;
  int blocksA = (Nh + 1) / 2;
  int blocksB = (N - Nh + 1) / 2;
  if (blocksA > 0)
    agg_kernel<<<blocksA, 256, 0, stream>>>(row_ptr, pairs, alpha_l, alpha_r, xbf, out, 0, Nh);
  if (blocksB > 0)
    agg_kernel<<<blocksB, 256, 0, stream>>>(row_ptr, pairs, alpha_l, alpha_r, xbf, out, Nh, N);
}

// Round 9
// 402.255 us; speedup vs baseline: 1.1084x; 1.0067x over previous
//
#include <hip/hip_runtime.h>
#include <stdint.h>

#define D_DIM 256
#define NPAD  640   // 256 (W_lin) + 256 (W_res) + 8 (att_l) + 8 (att_r) + 112 zero pad -> 5 x 128 tiles
#define NSH   8     // histogram shards (per-line atomic contention 1024 -> 128)

typedef __bf16 bf16x8 __attribute__((ext_vector_type(8)));
typedef float  f32x4  __attribute__((ext_vector_type(4)));

__device__ __forceinline__ float bf2f(unsigned short u) {
  union { unsigned int i; float f; } cv; cv.i = ((unsigned int)u) << 16; return cv.f;
}
__device__ __forceinline__ unsigned short f2bf(float f) {
  union { float f; unsigned int i; } cv; cv.f = f;
  unsigned int i = cv.i;
  unsigned int lsb = (i >> 16) & 1u;
  i += 0x7fffu + lsb;   // round-to-nearest-even
  return (unsigned short)(i >> 16);
}
__device__ __forceinline__ void gld16(const void* gptr, void* lptr) {
  __builtin_amdgcn_global_load_lds(
      (const __attribute__((address_space(1))) unsigned int*)gptr,
      (__attribute__((address_space(3))) unsigned int*)lptr, 16, 0, 0);
}

// ---------------- fused setup: [hist | cvt_feat | prep_bt] by block range ----------------
// R8 profile: this kernel was 77.6 us at VALUBusy 1.7% -- i.e. ~= the histogram's pure
// latency; cvt/prep (76.8 MB streaming) hides under it. Theory: per-CACHE-LINE atomic
// serialization (1.6M RMWs / 1562 lines of cnt = 1024/line x ~75 ns). Fix: shard the
// counters 8x by (e&7) with 200KB-apart regions -> 128 atomics/line. Rank within a node
// segment need not be arrival-order: any bijection works (agg reduction is commutative),
// so shard-major ordering within the segment is valid.
__global__ __launch_bounds__(256) void setup_fused(
    const float* __restrict__ feat, unsigned short* __restrict__ fb,
    const float* __restrict__ W_lin, const float* __restrict__ W_res,
    const float* __restrict__ att_l, const float* __restrict__ att_r,
    unsigned short* __restrict__ Bt, int nelem, int nb_hist, int nb_cvt,
    const int* __restrict__ dst, int* __restrict__ cntS, int* __restrict__ rank,
    int E, int Np) {
  int bid = blockIdx.x, t = threadIdx.x;
  if (bid < nb_hist) {
    int base = bid * 2048 + t;
    #pragma unroll
    for (int u = 0; u < 8; ++u) {
      int e = base + u * 256;
      if (e < E) {
        int d = dst[e];
        rank[e] = atomicAdd(&cntS[(e & (NSH - 1)) * Np + d], 1);
      }
    }
    return;
  }
  bid -= nb_hist;
  if (bid < nb_cvt) {
    int i = (bid * 256 + t) * 8;
    if (i >= nelem) return;
    float4 v0 = *(const float4*)(feat + i);
    float4 v1 = *(const float4*)(feat + i + 4);
    ushort4 a, b;
    a.x = f2bf(v0.x); a.y = f2bf(v0.y); a.z = f2bf(v0.z); a.w = f2bf(v0.w);
    b.x = f2bf(v1.x); b.y = f2bf(v1.y); b.z = f2bf(v1.z); b.w = f2bf(v1.w);
    *(ushort4*)(fb + i) = a;
    *(ushort4*)(fb + i + 4) = b;
  } else {
    int idx = (bid - nb_cvt) * 256 + t;   // covers NPAD*D_DIM exactly
    int n = idx >> 8, k = idx & 255;
    float v = 0.f;
    if (n < 256) v = W_lin[k * 256 + n];
    else if (n < 512) v = W_res[k * 256 + (n - 256)];
    else if (n < 520) {
      int h = n - 512; float s = 0.f;
      #pragma unroll
      for (int c = 0; c < 32; ++c) s += W_lin[k * 256 + h * 32 + c] * att_l[h * 32 + c];
      v = s;
    } else if (n < 528) {
      int h = n - 520; float s = 0.f;
      #pragma unroll
      for (int c = 0; c < 32; ++c) s += W_lin[k * 256 + h * 32 + c] * att_r[h * 32 + c];
      v = s;
    }
    Bt[idx] = f2bf(v);
  }
}

// ---------------- scans (2 launches; totals summed over shards) ----------------
__global__ __launch_bounds__(256) void scan_partial(const int* __restrict__ cntS,
                                                    int* __restrict__ bsum, int N, int Np) {
  __shared__ int s[256];
  int t = threadIdx.x;
  int i = blockIdx.x * 256 + t;
  int v = 0;
  if (i < N) {
    #pragma unroll
    for (int sh = 0; sh < NSH; ++sh) v += cntS[sh * Np + i];
  }
  s[t] = v;
  __syncthreads();
  for (int off = 128; off > 0; off >>= 1) {
    if (t < off) s[t] += s[t + off];
    __syncthreads();
  }
  if (t == 0) bsum[blockIdx.x] = s[0];
}

// scan_apply v4: folded top scan (R8) + per-(node,shard) offsets. For node i with
// exclusive base excl: row_ptr[i]=excl and soffA[sh][i] = excl + prefix(shard counts).
// soffA writes are coalesced per shard (consecutive i within a block).
__global__ __launch_bounds__(256) void scan_apply(const int* __restrict__ cntS,
                                                  const int* __restrict__ bsum,
                                                  int* __restrict__ row_ptr,
                                                  int* __restrict__ soffA, int N, int Np) {
  __shared__ int red[256];
  __shared__ int s[256];
  int t = threadIdx.x;
  int b = blockIdx.x;
  int acc = 0;
  for (int j = t; j < b; j += 256) acc += bsum[j];
  red[t] = acc;
  __syncthreads();
  for (int off = 128; off > 0; off >>= 1) {
    if (t < off) red[t] += red[t + off];
    __syncthreads();
  }
  int base = red[0];

  int i = b * 256 + t;
  int c[NSH]; int v = 0;
  if (i < N) {
    #pragma unroll
    for (int sh = 0; sh < NSH; ++sh) { c[sh] = cntS[sh * Np + i]; v += c[sh]; }
  }
  s[t] = v;
  __syncthreads();
  for (int off = 1; off < 256; off <<= 1) {
    int u = (t >= off) ? s[t - off] : 0;
    __syncthreads();
    s[t] += u;
    __syncthreads();
  }
  int excl = base + s[t] - v;
  if (i < N) {
    row_ptr[i] = excl;
    int run = excl;
    #pragma unroll
    for (int sh = 0; sh < NSH; ++sh) { soffA[sh * Np + i] = run; run += c[sh]; }
    if (i == N - 1) row_ptr[N] = excl + v;
  }
}

// ---------------- bf16 MFMA GEMM (BK=64, XOR-swizzled LDS, bm-major + XCD chunk) ----------------
__global__ __launch_bounds__(256) void gemm_kernel(
    const unsigned short* __restrict__ A,   // feat bf16 [M][256]
    const unsigned short* __restrict__ Bt,  // [640][256]
    float* __restrict__ out, unsigned short* __restrict__ xbf,
    float* __restrict__ alpha_l, float* __restrict__ alpha_r, int M, int gx) {
  __shared__ unsigned short As[128 * 64];
  __shared__ unsigned short Bs[128 * 64];

  int tid  = threadIdx.x;
  int w    = tid >> 6, lane = tid & 63;

  // bijective XCD-chunk swizzle (consecutive blockIdx -> consecutive XCDs on MI355X)
  int nwg  = (int)gridDim.x;
  int q    = nwg >> 3, r = nwg & 7;
  int xcd  = (int)blockIdx.x & 7, j = (int)blockIdx.x >> 3;
  int wg   = (xcd < r ? xcd * (q + 1) : r * (q + 1) + (xcd - r) * q) + j;

  int nbn  = NPAD / 128;                   // 5
  int bm   = (wg / nbn) * 128, bn = (wg % nbn) * 128;   // bm-major: A-tile reuse
  int wm   = (w & 1) * 64, wn = (w >> 1) * 64;
  int l16  = lane & 15, quad = lane >> 4;

  f32x4 acc[4][4] = {};

  int sr8     = lane >> 3;                       // row within 8-row staging group
  int koff_sw = (((lane & 7) ^ sr8) * 8);        // pre-swizzled source column (elements)

  for (int k0 = 0; k0 < 256; k0 += 64) {
    #pragma unroll
    for (int jj = 0; jj < 4; ++jj) {
      int rbase = w * 32 + jj * 8;
      int rga = bm + rbase + sr8; if (rga > M - 1) rga = M - 1;   // clamp (stores guarded)
      gld16(A  + (size_t)rga * 256 + k0 + koff_sw, &As[rbase * 64]);
      gld16(Bt + (size_t)(bn + rbase + sr8) * 256 + k0 + koff_sw, &Bs[rbase * 64]);
    }
    __syncthreads();
    #pragma unroll
    for (int kk = 0; kk < 64; kk += 32) {
      bf16x8 a[4], b[4];
      #pragma unroll
      for (int mi = 0; mi < 4; ++mi) {
        int rr = wm + mi * 16 + l16;
        int col = (kk * 2 + quad * 16) ^ ((rr & 7) << 4);   // byte col, same involution
        a[mi] = *(const bf16x8*)((const char*)&As[rr * 64] + col);
      }
      #pragma unroll
      for (int ni = 0; ni < 4; ++ni) {
        int rr = wn + ni * 16 + l16;
        int col = (kk * 2 + quad * 16) ^ ((rr & 7) << 4);
        b[ni] = *(const bf16x8*)((const char*)&Bs[rr * 64] + col);
      }
      #pragma unroll
      for (int mi = 0; mi < 4; ++mi)
        #pragma unroll
        for (int ni = 0; ni < 4; ++ni)
          acc[mi][ni] = __builtin_amdgcn_mfma_f32_16x16x32_bf16(a[mi], b[ni], acc[mi][ni], 0, 0, 0);
    }
    __syncthreads();
  }

  #pragma unroll
  for (int mi = 0; mi < 4; ++mi) {
    #pragma unroll
    for (int rr = 0; rr < 4; ++rr) {
      int row = bm + wm + mi * 16 + quad * 4 + rr;
      if (row >= M) continue;
      #pragma unroll
      for (int ni = 0; ni < 4; ++ni) {
        int n = bn + wn + ni * 16 + l16;
        float v = acc[mi][ni][rr];
        if (n < 256)      xbf[(size_t)row * 256 + n] = f2bf(v);
        else if (n < 512) out[(size_t)row * 256 + (n - 256)] = v;
        else if (n < 520) alpha_l[row * 8 + (n - 512)] = v;
        else if (n < 528) alpha_r[row * 8 + (n - 520)] = v;
      }
    }
  }
}

// ---------------- scatter (atomic-free, rank-based, shard-aware) ----------------
// pos = soffA[shard][d] + rank[e]; soffA already folds in row_ptr[d], so the gather count
// is unchanged vs the non-sharded version. Payload stays 8 B/edge (proven R2/R6).
__global__ __launch_bounds__(256) void scatter_kernel(
    const int* __restrict__ eidx, const float* __restrict__ ew,
    const int* __restrict__ soffA, const int* __restrict__ rank,
    int2* __restrict__ pairs, int E, int Np) {
  int e = blockIdx.x * 256 + threadIdx.x;
  if (e < E) {
    int d = eidx[E + e];
    int pos = soffA[(e & (NSH - 1)) * Np + d] + rank[e];
    int2 p; p.x = eidx[e]; p.y = __float_as_int(ew[e]);
    pairs[pos] = p;
  }
}

// ---------------- agg: 2 waves per dst node, alpha+exp in-loop (R3 form) ----------------
__global__ __launch_bounds__(256) void agg_kernel(
    const int* __restrict__ row_ptr, const int2* __restrict__ pairs,
    const float* __restrict__ alpha_l, const float* __restrict__ alpha_r,
    const unsigned short* __restrict__ xbf, float* __restrict__ out,
    int node_base, int node_lim) {
  __shared__ float red[2][64][6];        // [node-in-block][lane][l,ac0..3] (+pad)
  int nin  = threadIdx.x >> 7;           // node within block
  int wv   = (threadIdx.x >> 6) & 1;     // wave within node
  int lane = threadIdx.x & 63;
  int node = node_base + blockIdx.x * 2 + nin;
  bool active = node < node_lim;
  int h  = lane >> 3;                    // head for this lane's 4 channels
  int cb = lane << 2;                    // channel base (0..252)

  float l = 0.f, ac0 = 0.f, ac1 = 0.f, ac2 = 0.f, ac3 = 0.f;

  if (active) {
    int beg = row_ptr[node], end = row_ptr[node + 1];
    if (beg < end) {
      float arv = alpha_r[node * 8 + h];
      int last = end - 1;
      const unsigned short* xb = xbf + cb;
      for (int jg = beg + wv * 4; jg < end; jg += 8) {
        int2 q[4];
        #pragma unroll
        for (int u = 0; u < 4; ++u) {
          int t = jg + u; t = (t < last) ? t : last;   // clamp (masked below)
          q[u] = pairs[t];
        }
        float al[4];
        #pragma unroll
        for (int u = 0; u < 4; ++u) al[u] = alpha_l[(size_t)q[u].x * 8 + h];
        ushort4 xv[4];
        #pragma unroll
        for (int u = 0; u < 4; ++u)
          xv[u] = *(const ushort4*)(xb + ((size_t)q[u].x << 8));
        #pragma unroll
        for (int u = 0; u < 4; ++u) {
          float a = __int_as_float(q[u].y) * (al[u] + arv);
          a = (a > 0.f) ? a : 0.2f * a;            // leaky_relu(0.2)
          float p = __expf(a);
          p = (jg + u < end) ? p : 0.f;            // mask tail
          l += p;
          ac0 = fmaf(p, bf2f(xv[u].x), ac0);
          ac1 = fmaf(p, bf2f(xv[u].y), ac1);
          ac2 = fmaf(p, bf2f(xv[u].z), ac2);
          ac3 = fmaf(p, bf2f(xv[u].w), ac3);
        }
      }
    }
  }

  if (wv == 1) {
    red[nin][lane][0] = l;
    red[nin][lane][1] = ac0; red[nin][lane][2] = ac1;
    red[nin][lane][3] = ac2; red[nin][lane][4] = ac3;
  }
  __syncthreads();
  if (active && wv == 0) {
    l   += red[nin][lane][0];
    ac0 += red[nin][lane][1]; ac1 += red[nin][lane][2];
    ac2 += red[nin][lane][3]; ac3 += red[nin][lane][4];
    float r = 1.0f / (l + 1e-16f);
    float o0 = ac0 * r, o1 = ac1 * r, o2 = ac2 * r, o3 = ac3 * r;
    o0 = (o0 > 0.f) ? o0 : expm1f(o0);  // elu
    o1 = (o1 > 0.f) ? o1 : expm1f(o1);
    o2 = (o2 > 0.f) ? o2 : expm1f(o2);
    o3 = (o3 > 0.f) ? o3 : expm1f(o3);
    float4* op = (float4*)(out + ((size_t)node << 8) + cb);
    float4 res = *op;                    // residual written by gemm epilogue
    res.x += o0; res.y += o1; res.z += o2; res.w += o3;
    *op = res;
  }
}

extern "C" void kernel_launch(void* const* d_in, const int* in_sizes, int n_in,
                              void* d_out, int out_size, void* d_ws, size_t ws_size,
                              hipStream_t stream) {
  const float* feat  = (const float*)d_in[0];
  const float* ew    = (const float*)d_in[1];
  const float* W_lin = (const float*)d_in[2];
  const float* att_l = (const float*)d_in[3];
  const float* att_r = (const float*)d_in[4];
  const float* W_res = (const float*)d_in[5];
  const int*   eidx  = (const int*)d_in[6];
  float* out = (float*)d_out;

  int N = in_sizes[0] / D_DIM;
  int E = in_sizes[1];
  int Np = (N + 255) & ~255;            // padded shard stride

  char* p = (char*)d_ws;
  auto alloc = [&](size_t bytes) {
    char* r = p; p += (bytes + 255) & ~(size_t)255; return r;
  };
  unsigned short* xbf  = (unsigned short*)alloc((size_t)N * 256 * 2);   // 25.6 MB
  unsigned short* fb   = (unsigned short*)alloc((size_t)N * 256 * 2);   // 25.6 MB
  float* alpha_l       = (float*)alloc((size_t)N * 8 * 4);
  float* alpha_r       = (float*)alloc((size_t)N * 8 * 4);
  unsigned short* Bt   = (unsigned short*)alloc((size_t)NPAD * D_DIM * 2);
  int*   row_ptr       = (int*)alloc((size_t)(N + 1) * 4);
  int*   cntS          = (int*)alloc((size_t)NSH * Np * 4);             // 1.6 MB
  int*   soffA         = (int*)alloc((size_t)NSH * Np * 4);             // 1.6 MB
  int*   rank          = (int*)alloc((size_t)E * 4);
  int*   bsum          = (int*)alloc(1024);
  int2*  pairs_sep     = (int2*)alloc((size_t)E * 8);                   // 12.8 MB
  bool sep_ok = ((size_t)((char*)(pairs_sep + E) - (char*)d_ws) <= ws_size);
  // fallback: alias pairs onto fb (dead after gemm; scatter runs after gemm)
  int2* pairs = sep_ok ? pairs_sep : (int2*)fb;

  int nb      = (N + 255) / 256;
  int nb_cvt  = (N * 256 / 8 + 255) / 256;
  int nb_prep = NPAD * D_DIM / 256;
  int nb_hist = (E + 2047) / 2048;    // 8 edges/thread
  int nb_scat = (E + 255) / 256;
  int gx = (N + 127) / 128;
  int gemm_blocks = gx * (NPAD / 128);

  hipMemsetAsync(cntS, 0, (size_t)NSH * Np * 4, stream);

  setup_fused<<<nb_hist + nb_cvt + nb_prep, 256, 0, stream>>>(
      feat, fb, W_lin, W_res, att_l, att_r, Bt, N * 256, nb_hist, nb_cvt,
      eidx + E, cntS, rank, E, Np);

  gemm_kernel<<<gemm_blocks, 256, 0, stream>>>(
      fb, Bt, out, xbf, alpha_l, alpha_r, N, gx);

  scan_partial<<<nb, 256, 0, stream>>>(cntS, bsum, N, Np);
  scan_apply<<<nb, 256, 0, stream>>>(cntS, bsum, row_ptr, soffA, N, Np);

  scatter_kernel<<<nb_scat, 256, 0, stream>>>(eidx, ew, soffA, rank, pairs, E, Np);

  // agg split into two half-grids (keeps production kernels visible in top-5)
  int Nh = ((N / 2) + 1) & ~1;            // even split point
  if (Nh > N) Nh = N;
  int blocksA = (Nh + 1) / 2;
  int blocksB = (N - Nh + 1) / 2;
  if (blocksA > 0)
    agg_kernel<<<blocksA, 256, 0, stream>>>(row_ptr, pairs, alpha_l, alpha_r, xbf, out, 0, Nh);
  if (blocksB > 0)
    agg_kernel<<<blocksB, 256, 0, stream>>>(row_ptr, pairs, alpha_l, alpha_r, xbf, out, Nh, N);
}

// Round 10
// 400.306 us; speedup vs baseline: 1.1138x; 1.0049x over previous
//
#include <hip/hip_runtime.h>
#include <stdint.h>

#define D_DIM 256
#define NPAD  640   // 256 (W_lin) + 256 (W_res) + 8 (att_l) + 8 (att_r) + 112 zero pad -> 5 x 128 tiles
#define NSH   8     // histogram shards (kept from R9: marginal +4 us, harmless)

typedef __bf16 bf16x8 __attribute__((ext_vector_type(8)));
typedef float  f32x4  __attribute__((ext_vector_type(4)));

__device__ __forceinline__ float bf2f(unsigned short u) {
  union { unsigned int i; float f; } cv; cv.i = ((unsigned int)u) << 16; return cv.f;
}
__device__ __forceinline__ unsigned short f2bf(float f) {
  union { float f; unsigned int i; } cv; cv.f = f;
  unsigned int i = cv.i;
  unsigned int lsb = (i >> 16) & 1u;
  i += 0x7fffu + lsb;   // round-to-nearest-even
  return (unsigned short)(i >> 16);
}
__device__ __forceinline__ void gld16(const void* gptr, void* lptr) {
  __builtin_amdgcn_global_load_lds(
      (const __attribute__((address_space(1))) unsigned int*)gptr,
      (__attribute__((address_space(3))) unsigned int*)lptr, 16, 0, 0);
}

// ---------------- setup: [cvt_feat | prep_bt] (hist moved into gemm tail) ----------------
__global__ __launch_bounds__(256) void setup_cvt_prep(
    const float* __restrict__ feat, unsigned short* __restrict__ fb,
    const float* __restrict__ W_lin, const float* __restrict__ W_res,
    const float* __restrict__ att_l, const float* __restrict__ att_r,
    unsigned short* __restrict__ Bt, int nelem, int nb_cvt) {
  int bid = blockIdx.x, t = threadIdx.x;
  if (bid < nb_cvt) {
    int i = (bid * 256 + t) * 8;
    if (i >= nelem) return;
    float4 v0 = *(const float4*)(feat + i);
    float4 v1 = *(const float4*)(feat + i + 4);
    ushort4 a, b;
    a.x = f2bf(v0.x); a.y = f2bf(v0.y); a.z = f2bf(v0.z); a.w = f2bf(v0.w);
    b.x = f2bf(v1.x); b.y = f2bf(v1.y); b.z = f2bf(v1.z); b.w = f2bf(v1.w);
    *(ushort4*)(fb + i) = a;
    *(ushort4*)(fb + i + 4) = b;
  } else {
    int idx = (bid - nb_cvt) * 256 + t;   // covers NPAD*D_DIM exactly
    int n = idx >> 8, k = idx & 255;
    float v = 0.f;
    if (n < 256) v = W_lin[k * 256 + n];
    else if (n < 512) v = W_res[k * 256 + (n - 256)];
    else if (n < 520) {
      int h = n - 512; float s = 0.f;
      #pragma unroll
      for (int c = 0; c < 32; ++c) s += W_lin[k * 256 + h * 32 + c] * att_l[h * 32 + c];
      v = s;
    } else if (n < 528) {
      int h = n - 520; float s = 0.f;
      #pragma unroll
      for (int c = 0; c < 32; ++c) s += W_lin[k * 256 + h * 32 + c] * att_r[h * 32 + c];
      v = s;
    }
    Bt[idx] = f2bf(v);
  }
}

// ---------------- scans (2 launches; totals summed over shards) ----------------
__global__ __launch_bounds__(256) void scan_partial(const int* __restrict__ cntS,
                                                    int* __restrict__ bsum, int N, int Np) {
  __shared__ int s[256];
  int t = threadIdx.x;
  int i = blockIdx.x * 256 + t;
  int v = 0;
  if (i < N) {
    #pragma unroll
    for (int sh = 0; sh < NSH; ++sh) v += cntS[sh * Np + i];
  }
  s[t] = v;
  __syncthreads();
  for (int off = 128; off > 0; off >>= 1) {
    if (t < off) s[t] += s[t + off];
    __syncthreads();
  }
  if (t == 0) bsum[blockIdx.x] = s[0];
}

__global__ __launch_bounds__(256) void scan_apply(const int* __restrict__ cntS,
                                                  const int* __restrict__ bsum,
                                                  int* __restrict__ row_ptr,
                                                  int* __restrict__ soffA, int N, int Np) {
  __shared__ int red[256];
  __shared__ int s[256];
  int t = threadIdx.x;
  int b = blockIdx.x;
  int acc = 0;
  for (int j = t; j < b; j += 256) acc += bsum[j];
  red[t] = acc;
  __syncthreads();
  for (int off = 128; off > 0; off >>= 1) {
    if (t < off) red[t] += red[t + off];
    __syncthreads();
  }
  int base = red[0];

  int i = b * 256 + t;
  int c[NSH]; int v = 0;
  if (i < N) {
    #pragma unroll
    for (int sh = 0; sh < NSH; ++sh) { c[sh] = cntS[sh * Np + i]; v += c[sh]; }
  }
  s[t] = v;
  __syncthreads();
  for (int off = 1; off < 256; off <<= 1) {
    int u = (t >= off) ? s[t - off] : 0;
    __syncthreads();
    s[t] += u;
    __syncthreads();
  }
  int excl = base + s[t] - v;
  if (i < N) {
    row_ptr[i] = excl;
    int run = excl;
    #pragma unroll
    for (int sh = 0; sh < NSH; ++sh) { soffA[sh * Np + i] = run; run += c[sh]; }
    if (i == N - 1) row_ptr[N] = excl + v;
  }
}

// ---------------- bf16 MFMA GEMM + hist tail ----------------
// R9 falsified line-contention (8x sharding: 77.6 -> 73.4 us): hist is bound by the
// fabric's scattered-RMW SERVICE RATE (~22 G/s, all 1.6M atomics already in flight).
// It can't be reduced -- but it CAN be hidden: the GEMM uses MFMA/LDS/streaming reads,
// disjoint from the RMW pipe. Each block processes an edge slice AFTER its epilogue, so
// atomic bursts stagger across block completion times; only the last round's drain
// (~512 blocks x 819 / 22G ~ 19 us) is exposed. Differs from R2's failed fusion in
// dispatch order (hist-first gated the machine) and granularity (per-block tail).
__global__ __launch_bounds__(256) void gemm_kernel(
    const unsigned short* __restrict__ A,   // feat bf16 [M][256]
    const unsigned short* __restrict__ Bt,  // [640][256]
    float* __restrict__ out, unsigned short* __restrict__ xbf,
    float* __restrict__ alpha_l, float* __restrict__ alpha_r, int M, int gx,
    const int* __restrict__ dst, int* __restrict__ cntS, int* __restrict__ rank,
    int E, int Np, int echunk) {
  __shared__ unsigned short As[128 * 64];
  __shared__ unsigned short Bs[128 * 64];

  int tid  = threadIdx.x;
  int w    = tid >> 6, lane = tid & 63;

  // bijective XCD-chunk swizzle (consecutive blockIdx -> consecutive XCDs on MI355X)
  int nwg  = (int)gridDim.x;
  int q    = nwg >> 3, r = nwg & 7;
  int xcd  = (int)blockIdx.x & 7, j = (int)blockIdx.x >> 3;
  int wg   = (xcd < r ? xcd * (q + 1) : r * (q + 1) + (xcd - r) * q) + j;

  int nbn  = NPAD / 128;                   // 5
  int bm   = (wg / nbn) * 128, bn = (wg % nbn) * 128;   // bm-major: A-tile reuse
  int wm   = (w & 1) * 64, wn = (w >> 1) * 64;
  int l16  = lane & 15, quad = lane >> 4;

  f32x4 acc[4][4] = {};

  int sr8     = lane >> 3;                       // row within 8-row staging group
  int koff_sw = (((lane & 7) ^ sr8) * 8);        // pre-swizzled source column (elements)

  for (int k0 = 0; k0 < 256; k0 += 64) {
    #pragma unroll
    for (int jj = 0; jj < 4; ++jj) {
      int rbase = w * 32 + jj * 8;
      int rga = bm + rbase + sr8; if (rga > M - 1) rga = M - 1;   // clamp (stores guarded)
      gld16(A  + (size_t)rga * 256 + k0 + koff_sw, &As[rbase * 64]);
      gld16(Bt + (size_t)(bn + rbase + sr8) * 256 + k0 + koff_sw, &Bs[rbase * 64]);
    }
    __syncthreads();
    #pragma unroll
    for (int kk = 0; kk < 64; kk += 32) {
      bf16x8 a[4], b[4];
      #pragma unroll
      for (int mi = 0; mi < 4; ++mi) {
        int rr = wm + mi * 16 + l16;
        int col = (kk * 2 + quad * 16) ^ ((rr & 7) << 4);   // byte col, same involution
        a[mi] = *(const bf16x8*)((const char*)&As[rr * 64] + col);
      }
      #pragma unroll
      for (int ni = 0; ni < 4; ++ni) {
        int rr = wn + ni * 16 + l16;
        int col = (kk * 2 + quad * 16) ^ ((rr & 7) << 4);
        b[ni] = *(const bf16x8*)((const char*)&Bs[rr * 64] + col);
      }
      #pragma unroll
      for (int mi = 0; mi < 4; ++mi)
        #pragma unroll
        for (int ni = 0; ni < 4; ++ni)
          acc[mi][ni] = __builtin_amdgcn_mfma_f32_16x16x32_bf16(a[mi], b[ni], acc[mi][ni], 0, 0, 0);
    }
    __syncthreads();
  }

  #pragma unroll
  for (int mi = 0; mi < 4; ++mi) {
    #pragma unroll
    for (int rr = 0; rr < 4; ++rr) {
      int row = bm + wm + mi * 16 + quad * 4 + rr;
      if (row >= M) continue;
      #pragma unroll
      for (int ni = 0; ni < 4; ++ni) {
        int n = bn + wn + ni * 16 + l16;
        float v = acc[mi][ni][rr];
        if (n < 256)      xbf[(size_t)row * 256 + n] = f2bf(v);
        else if (n < 512) out[(size_t)row * 256 + (n - 256)] = v;
        else if (n < 520) alpha_l[row * 8 + (n - 512)] = v;
        else if (n < 528) alpha_r[row * 8 + (n - 520)] = v;
      }
    }
  }

  // ---- hist tail: this block's edge slice (raw blockIdx -- any bijection is fine) ----
  int ebase = (int)blockIdx.x * echunk;
  int elim  = ebase + echunk; if (elim > E) elim = E;
  for (int e = ebase + tid; e < elim; e += 256) {
    int d = dst[e];
    rank[e] = atomicAdd(&cntS[(e & (NSH - 1)) * Np + d], 1);
  }
}

// ---------------- scatter (atomic-free, rank-based, shard-aware) ----------------
__global__ __launch_bounds__(256) void scatter_kernel(
    const int* __restrict__ eidx, const float* __restrict__ ew,
    const int* __restrict__ soffA, const int* __restrict__ rank,
    int2* __restrict__ pairs, int E, int Np) {
  int e = blockIdx.x * 256 + threadIdx.x;
  if (e < E) {
    int d = eidx[E + e];
    int pos = soffA[(e & (NSH - 1)) * Np + d] + rank[e];
    int2 p; p.x = eidx[e]; p.y = __float_as_int(ew[e]);
    pairs[pos] = p;
  }
}

// ---------------- agg: 2 waves per dst node, alpha+exp in-loop (R3 form, single launch) ----------------
// R9 quantified the half-split diagnostic cost (~6.5 us: 73+73 vs 139.5) -> merged back.
__global__ __launch_bounds__(256) void agg_kernel(
    const int* __restrict__ row_ptr, const int2* __restrict__ pairs,
    const float* __restrict__ alpha_l, const float* __restrict__ alpha_r,
    const unsigned short* __restrict__ xbf, float* __restrict__ out, int N) {
  __shared__ float red[2][64][6];        // [node-in-block][lane][l,ac0..3] (+pad)
  int nin  = threadIdx.x >> 7;           // node within block
  int wv   = (threadIdx.x >> 6) & 1;     // wave within node
  int lane = threadIdx.x & 63;
  int node = blockIdx.x * 2 + nin;
  bool active = node < N;
  int h  = lane >> 3;                    // head for this lane's 4 channels
  int cb = lane << 2;                    // channel base (0..252)

  float l = 0.f, ac0 = 0.f, ac1 = 0.f, ac2 = 0.f, ac3 = 0.f;

  if (active) {
    int beg = row_ptr[node], end = row_ptr[node + 1];
    if (beg < end) {
      float arv = alpha_r[node * 8 + h];
      int last = end - 1;
      const unsigned short* xb = xbf + cb;
      for (int jg = beg + wv * 4; jg < end; jg += 8) {
        int2 q[4];
        #pragma unroll
        for (int u = 0; u < 4; ++u) {
          int t = jg + u; t = (t < last) ? t : last;   // clamp (masked below)
          q[u] = pairs[t];
        }
        float al[4];
        #pragma unroll
        for (int u = 0; u < 4; ++u) al[u] = alpha_l[(size_t)q[u].x * 8 + h];
        ushort4 xv[4];
        #pragma unroll
        for (int u = 0; u < 4; ++u)
          xv[u] = *(const ushort4*)(xb + ((size_t)q[u].x << 8));
        #pragma unroll
        for (int u = 0; u < 4; ++u) {
          float a = __int_as_float(q[u].y) * (al[u] + arv);
          a = (a > 0.f) ? a : 0.2f * a;            // leaky_relu(0.2)
          float p = __expf(a);
          p = (jg + u < end) ? p : 0.f;            // mask tail
          l += p;
          ac0 = fmaf(p, bf2f(xv[u].x), ac0);
          ac1 = fmaf(p, bf2f(xv[u].y), ac1);
          ac2 = fmaf(p, bf2f(xv[u].z), ac2);
          ac3 = fmaf(p, bf2f(xv[u].w), ac3);
        }
      }
    }
  }

  if (wv == 1) {
    red[nin][lane][0] = l;
    red[nin][lane][1] = ac0; red[nin][lane][2] = ac1;
    red[nin][lane][3] = ac2; red[nin][lane][4] = ac3;
  }
  __syncthreads();
  if (active && wv == 0) {
    l   += red[nin][lane][0];
    ac0 += red[nin][lane][1]; ac1 += red[nin][lane][2];
    ac2 += red[nin][lane][3]; ac3 += red[nin][lane][4];
    float r = 1.0f / (l + 1e-16f);
    float o0 = ac0 * r, o1 = ac1 * r, o2 = ac2 * r, o3 = ac3 * r;
    o0 = (o0 > 0.f) ? o0 : expm1f(o0);  // elu
    o1 = (o1 > 0.f) ? o1 : expm1f(o1);
    o2 = (o2 > 0.f) ? o2 : expm1f(o2);
    o3 = (o3 > 0.f) ? o3 : expm1f(o3);
    float4* op = (float4*)(out + ((size_t)node << 8) + cb);
    float4 res = *op;                    // residual written by gemm epilogue
    res.x += o0; res.y += o1; res.z += o2; res.w += o3;
    *op = res;
  }
}

extern "C" void kernel_launch(void* const* d_in, const int* in_sizes, int n_in,
                              void* d_out, int out_size, void* d_ws, size_t ws_size,
                              hipStream_t stream) {
  const float* feat  = (const float*)d_in[0];
  const float* ew    = (const float*)d_in[1];
  const float* W_lin = (const float*)d_in[2];
  const float* att_l = (const float*)d_in[3];
  const float* att_r = (const float*)d_in[4];
  const float* W_res = (const float*)d_in[5];
  const int*   eidx  = (const int*)d_in[6];
  float* out = (float*)d_out;

  int N = in_sizes[0] / D_DIM;
  int E = in_sizes[1];
  int Np = (N + 255) & ~255;            // padded shard stride

  char* p = (char*)d_ws;
  auto alloc = [&](size_t bytes) {
    char* r = p; p += (bytes + 255) & ~(size_t)255; return r;
  };
  unsigned short* xbf  = (unsigned short*)alloc((size_t)N * 256 * 2);   // 25.6 MB
  unsigned short* fb   = (unsigned short*)alloc((size_t)N * 256 * 2);   // 25.6 MB
  float* alpha_l       = (float*)alloc((size_t)N * 8 * 4);
  float* alpha_r       = (float*)alloc((size_t)N * 8 * 4);
  unsigned short* Bt   = (unsigned short*)alloc((size_t)NPAD * D_DIM * 2);
  int*   row_ptr       = (int*)alloc((size_t)(N + 1) * 4);
  int*   cntS          = (int*)alloc((size_t)NSH * Np * 4);             // 1.6 MB
  int*   soffA         = (int*)alloc((size_t)NSH * Np * 4);             // 1.6 MB
  int*   rank          = (int*)alloc((size_t)E * 4);
  int*   bsum          = (int*)alloc(1024);
  int2*  pairs_sep     = (int2*)alloc((size_t)E * 8);                   // 12.8 MB
  bool sep_ok = ((size_t)((char*)(pairs_sep + E) - (char*)d_ws) <= ws_size);
  // fallback: alias pairs onto fb (dead after gemm; scatter runs after gemm)
  int2* pairs = sep_ok ? pairs_sep : (int2*)fb;

  int nb      = (N + 255) / 256;
  int nb_cvt  = (N * 256 / 8 + 255) / 256;
  int nb_prep = NPAD * D_DIM / 256;
  int nb_scat = (E + 255) / 256;
  int gx = (N + 127) / 128;
  int gemm_blocks = gx * (NPAD / 128);
  int echunk = (E + gemm_blocks - 1) / gemm_blocks;   // ~819 edges per gemm block

  hipMemsetAsync(cntS, 0, (size_t)NSH * Np * 4, stream);

  setup_cvt_prep<<<nb_cvt + nb_prep, 256, 0, stream>>>(
      feat, fb, W_lin, W_res, att_l, att_r, Bt, N * 256, nb_cvt);

  gemm_kernel<<<gemm_blocks, 256, 0, stream>>>(
      fb, Bt, out, xbf, alpha_l, alpha_r, N, gx,
      eidx + E, cntS, rank, E, Np, echunk);

  scan_partial<<<nb, 256, 0, stream>>>(cntS, bsum, N, Np);
  scan_apply<<<nb, 256, 0, stream>>>(cntS, bsum, row_ptr, soffA, N, Np);

  scatter_kernel<<<nb_scat, 256, 0, stream>>>(eidx, ew, soffA, rank, pairs, E, Np);

  agg_kernel<<<(N + 1) / 2, 256, 0, stream>>>(row_ptr, pairs, alpha_l, alpha_r, xbf, out, N);
}

// Round 11
// 394.591 us; speedup vs baseline: 1.1299x; 1.0145x over previous
//
#include <hip/hip_runtime.h>
#include <stdint.h>

#define D_DIM 256
#define NPAD  640   // 256 (W_lin) + 256 (W_res) + 8 (att_l) + 8 (att_r) + 112 zero pad -> 5 x 128 tiles
#define NSH   8     // histogram shards (R9: marginal but harmless)

typedef __bf16 bf16x8 __attribute__((ext_vector_type(8)));
typedef float  f32x4  __attribute__((ext_vector_type(4)));

__device__ __forceinline__ float bf2f(unsigned short u) {
  union { unsigned int i; float f; } cv; cv.i = ((unsigned int)u) << 16; return cv.f;
}
__device__ __forceinline__ unsigned short f2bf(float f) {
  union { float f; unsigned int i; } cv; cv.f = f;
  unsigned int i = cv.i;
  unsigned int lsb = (i >> 16) & 1u;
  i += 0x7fffu + lsb;   // round-to-nearest-even
  return (unsigned short)(i >> 16);
}
__device__ __forceinline__ void gld16(const void* gptr, void* lptr) {
  __builtin_amdgcn_global_load_lds(
      (const __attribute__((address_space(1))) unsigned int*)gptr,
      (__attribute__((address_space(3))) unsigned int*)lptr, 16, 0, 0);
}

// ---------------- setup: [cvt_feat | prep_bt] ----------------
__global__ __launch_bounds__(256) void setup_cvt_prep(
    const float* __restrict__ feat, unsigned short* __restrict__ fb,
    const float* __restrict__ W_lin, const float* __restrict__ W_res,
    const float* __restrict__ att_l, const float* __restrict__ att_r,
    unsigned short* __restrict__ Bt, int nelem, int nb_cvt) {
  int bid = blockIdx.x, t = threadIdx.x;
  if (bid < nb_cvt) {
    int i = (bid * 256 + t) * 8;
    if (i >= nelem) return;
    float4 v0 = *(const float4*)(feat + i);
    float4 v1 = *(const float4*)(feat + i + 4);
    ushort4 a, b;
    a.x = f2bf(v0.x); a.y = f2bf(v0.y); a.z = f2bf(v0.z); a.w = f2bf(v0.w);
    b.x = f2bf(v1.x); b.y = f2bf(v1.y); b.z = f2bf(v1.z); b.w = f2bf(v1.w);
    *(ushort4*)(fb + i) = a;
    *(ushort4*)(fb + i + 4) = b;
  } else {
    int idx = (bid - nb_cvt) * 256 + t;   // covers NPAD*D_DIM exactly
    int n = idx >> 8, k = idx & 255;
    float v = 0.f;
    if (n < 256) v = W_lin[k * 256 + n];
    else if (n < 512) v = W_res[k * 256 + (n - 256)];
    else if (n < 520) {
      int h = n - 512; float s = 0.f;
      #pragma unroll
      for (int c = 0; c < 32; ++c) s += W_lin[k * 256 + h * 32 + c] * att_l[h * 32 + c];
      v = s;
    } else if (n < 528) {
      int h = n - 520; float s = 0.f;
      #pragma unroll
      for (int c = 0; c < 32; ++c) s += W_lin[k * 256 + h * 32 + c] * att_r[h * 32 + c];
      v = s;
    }
    Bt[idx] = f2bf(v);
  }
}

// ---------------- scans (2 launches; totals summed over shards) ----------------
__global__ __launch_bounds__(256) void scan_partial(const int* __restrict__ cntS,
                                                    int* __restrict__ bsum, int N, int Np) {
  __shared__ int s[256];
  int t = threadIdx.x;
  int i = blockIdx.x * 256 + t;
  int v = 0;
  if (i < N) {
    #pragma unroll
    for (int sh = 0; sh < NSH; ++sh) v += cntS[sh * Np + i];
  }
  s[t] = v;
  __syncthreads();
  for (int off = 128; off > 0; off >>= 1) {
    if (t < off) s[t] += s[t + off];
    __syncthreads();
  }
  if (t == 0) bsum[blockIdx.x] = s[0];
}

__global__ __launch_bounds__(256) void scan_apply(const int* __restrict__ cntS,
                                                  const int* __restrict__ bsum,
                                                  int* __restrict__ row_ptr,
                                                  int* __restrict__ soffA, int N, int Np) {
  __shared__ int red[256];
  __shared__ int s[256];
  int t = threadIdx.x;
  int b = blockIdx.x;
  int acc = 0;
  for (int j = t; j < b; j += 256) acc += bsum[j];
  red[t] = acc;
  __syncthreads();
  for (int off = 128; off > 0; off >>= 1) {
    if (t < off) red[t] += red[t + off];
    __syncthreads();
  }
  int base = red[0];

  int i = b * 256 + t;
  int c[NSH]; int v = 0;
  if (i < N) {
    #pragma unroll
    for (int sh = 0; sh < NSH; ++sh) { c[sh] = cntS[sh * Np + i]; v += c[sh]; }
  }
  s[t] = v;
  __syncthreads();
  for (int off = 1; off < 256; off <<= 1) {
    int u = (t >= off) ? s[t - off] : 0;
    __syncthreads();
    s[t] += u;
    __syncthreads();
  }
  int excl = base + s[t] - v;
  if (i < N) {
    row_ptr[i] = excl;
    int run = excl;
    #pragma unroll
    for (int sh = 0; sh < NSH; ++sh) { soffA[sh * Np + i] = run; run += c[sh]; }
    if (i == N - 1) row_ptr[N] = excl + v;
  }
}

// ---------------- fused [gemm | hist] with INTERLEAVED role blocks ----------------
// Fusion ledger: R2 hist-FIRST = 117 us (partial overlap, hist gated machine).
// R10 hist-as-per-block-TAIL = 146 us ~= serial (tails align across occupancy rounds +
// the strided tail loop held only 1 RMW in flight/thread). This round: dedicated hist
// blocks INTERLEAVED 1-per-6 through dispatch order (exact: gemm_blocks = gx*5, nh = gx)
// -> both roles co-resident for the whole kernel; the fabric's scattered-RMW service
// (~22 G/s, R9-measured) runs under MFMA/LDS compute, which use disjoint resources.
// Hist blocks use the R9-proven deep unroll: 16 independent RMWs in flight per thread.
__global__ __launch_bounds__(256) void gemm_hist(
    const unsigned short* __restrict__ A,   // feat bf16 [M][256]
    const unsigned short* __restrict__ Bt,  // [640][256]
    float* __restrict__ out, unsigned short* __restrict__ xbf,
    float* __restrict__ alpha_l, float* __restrict__ alpha_r, int M, int gx,
    const int* __restrict__ dst, int* __restrict__ cntS, int* __restrict__ rank,
    int E, int Np, int echunk) {
  __shared__ unsigned short As[128 * 64];
  __shared__ unsigned short Bs[128 * 64];

  int tid  = threadIdx.x;
  int bid  = (int)blockIdx.x;
  int grp  = bid / 6, pos = bid - grp * 6;

  if (pos == 5) {
    // ---- hist role: 1 block per group of 6, co-resident with gemm blocks ----
    int ebase = grp * echunk;
    int elim  = ebase + echunk; if (elim > E) elim = E;
    for (int eb = ebase; eb < elim; eb += 4096) {
      #pragma unroll
      for (int u = 0; u < 16; ++u) {              // 16 independent RMWs in flight
        int e = eb + u * 256 + tid;
        if (e < elim) {
          int d = dst[e];
          rank[e] = atomicAdd(&cntS[(e & (NSH - 1)) * Np + d], 1);
        }
      }
    }
    return;
  }

  int w    = tid >> 6, lane = tid & 63;
  int gb   = grp * 5 + pos;                       // gemm tile index in [0, gx*5)

  // bijective XCD-chunk swizzle over the gemm-tile space (ng = gx*5)
  int ng   = gx * 5;
  int q    = ng >> 3, r = ng & 7;
  int xcd  = gb & 7, j = gb >> 3;
  int wg   = (xcd < r ? xcd * (q + 1) : r * (q + 1) + (xcd - r) * q) + j;

  int nbn  = NPAD / 128;                   // 5
  int bm   = (wg / nbn) * 128, bn = (wg % nbn) * 128;   // bm-major: A-tile reuse
  int wm   = (w & 1) * 64, wn = (w >> 1) * 64;
  int l16  = lane & 15, quad = lane >> 4;

  f32x4 acc[4][4] = {};

  int sr8     = lane >> 3;                       // row within 8-row staging group
  int koff_sw = (((lane & 7) ^ sr8) * 8);        // pre-swizzled source column (elements)

  for (int k0 = 0; k0 < 256; k0 += 64) {
    #pragma unroll
    for (int jj = 0; jj < 4; ++jj) {
      int rbase = w * 32 + jj * 8;
      int rga = bm + rbase + sr8; if (rga > M - 1) rga = M - 1;   // clamp (stores guarded)
      gld16(A  + (size_t)rga * 256 + k0 + koff_sw, &As[rbase * 64]);
      gld16(Bt + (size_t)(bn + rbase + sr8) * 256 + k0 + koff_sw, &Bs[rbase * 64]);
    }
    __syncthreads();
    #pragma unroll
    for (int kk = 0; kk < 64; kk += 32) {
      bf16x8 a[4], b[4];
      #pragma unroll
      for (int mi = 0; mi < 4; ++mi) {
        int rr = wm + mi * 16 + l16;
        int col = (kk * 2 + quad * 16) ^ ((rr & 7) << 4);   // byte col, same involution
        a[mi] = *(const bf16x8*)((const char*)&As[rr * 64] + col);
      }
      #pragma unroll
      for (int ni = 0; ni < 4; ++ni) {
        int rr = wn + ni * 16 + l16;
        int col = (kk * 2 + quad * 16) ^ ((rr & 7) << 4);
        b[ni] = *(const bf16x8*)((const char*)&Bs[rr * 64] + col);
      }
      #pragma unroll
      for (int mi = 0; mi < 4; ++mi)
        #pragma unroll
        for (int ni = 0; ni < 4; ++ni)
          acc[mi][ni] = __builtin_amdgcn_mfma_f32_16x16x32_bf16(a[mi], b[ni], acc[mi][ni], 0, 0, 0);
    }
    __syncthreads();
  }

  #pragma unroll
  for (int mi = 0; mi < 4; ++mi) {
    #pragma unroll
    for (int rr = 0; rr < 4; ++rr) {
      int row = bm + wm + mi * 16 + quad * 4 + rr;
      if (row >= M) continue;
      #pragma unroll
      for (int ni = 0; ni < 4; ++ni) {
        int n = bn + wn + ni * 16 + l16;
        float v = acc[mi][ni][rr];
        if (n < 256)      xbf[(size_t)row * 256 + n] = f2bf(v);
        else if (n < 512) out[(size_t)row * 256 + (n - 256)] = v;
        else if (n < 520) alpha_l[row * 8 + (n - 512)] = v;
        else if (n < 528) alpha_r[row * 8 + (n - 520)] = v;
      }
    }
  }
}

// ---------------- scatter (atomic-free, rank-based, shard-aware) ----------------
__global__ __launch_bounds__(256) void scatter_kernel(
    const int* __restrict__ eidx, const float* __restrict__ ew,
    const int* __restrict__ soffA, const int* __restrict__ rank,
    int2* __restrict__ pairs, int E, int Np) {
  int e = blockIdx.x * 256 + threadIdx.x;
  if (e < E) {
    int d = eidx[E + e];
    int pos = soffA[(e & (NSH - 1)) * Np + d] + rank[e];
    int2 p; p.x = eidx[e]; p.y = __float_as_int(ew[e]);
    pairs[pos] = p;
  }
}

// ---------------- agg: 2 waves per dst node, alpha+exp in-loop (R3 form) ----------------
__global__ __launch_bounds__(256) void agg_kernel(
    const int* __restrict__ row_ptr, const int2* __restrict__ pairs,
    const float* __restrict__ alpha_l, const float* __restrict__ alpha_r,
    const unsigned short* __restrict__ xbf, float* __restrict__ out, int N) {
  __shared__ float red[2][64][6];        // [node-in-block][lane][l,ac0..3] (+pad)
  int nin  = threadIdx.x >> 7;           // node within block
  int wv   = (threadIdx.x >> 6) & 1;     // wave within node
  int lane = threadIdx.x & 63;
  int node = blockIdx.x * 2 + nin;
  bool active = node < N;
  int h  = lane >> 3;                    // head for this lane's 4 channels
  int cb = lane << 2;                    // channel base (0..252)

  float l = 0.f, ac0 = 0.f, ac1 = 0.f, ac2 = 0.f, ac3 = 0.f;

  if (active) {
    int beg = row_ptr[node], end = row_ptr[node + 1];
    if (beg < end) {
      float arv = alpha_r[node * 8 + h];
      int last = end - 1;
      const unsigned short* xb = xbf + cb;
      for (int jg = beg + wv * 4; jg < end; jg += 8) {
        int2 q[4];
        #pragma unroll
        for (int u = 0; u < 4; ++u) {
          int t = jg + u; t = (t < last) ? t : last;   // clamp (masked below)
          q[u] = pairs[t];
        }
        float al[4];
        #pragma unroll
        for (int u = 0; u < 4; ++u) al[u] = alpha_l[(size_t)q[u].x * 8 + h];
        ushort4 xv[4];
        #pragma unroll
        for (int u = 0; u < 4; ++u)
          xv[u] = *(const ushort4*)(xb + ((size_t)q[u].x << 8));
        #pragma unroll
        for (int u = 0; u < 4; ++u) {
          float a = __int_as_float(q[u].y) * (al[u] + arv);
          a = (a > 0.f) ? a : 0.2f * a;            // leaky_relu(0.2)
          float p = __expf(a);
          p = (jg + u < end) ? p : 0.f;            // mask tail
          l += p;
          ac0 = fmaf(p, bf2f(xv[u].x), ac0);
          ac1 = fmaf(p, bf2f(xv[u].y), ac1);
          ac2 = fmaf(p, bf2f(xv[u].z), ac2);
          ac3 = fmaf(p, bf2f(xv[u].w), ac3);
        }
      }
    }
  }

  if (wv == 1) {
    red[nin][lane][0] = l;
    red[nin][lane][1] = ac0; red[nin][lane][2] = ac1;
    red[nin][lane][3] = ac2; red[nin][lane][4] = ac3;
  }
  __syncthreads();
  if (active && wv == 0) {
    l   += red[nin][lane][0];
    ac0 += red[nin][lane][1]; ac1 += red[nin][lane][2];
    ac2 += red[nin][lane][3]; ac3 += red[nin][lane][4];
    float r = 1.0f / (l + 1e-16f);
    float o0 = ac0 * r, o1 = ac1 * r, o2 = ac2 * r, o3 = ac3 * r;
    o0 = (o0 > 0.f) ? o0 : expm1f(o0);  // elu
    o1 = (o1 > 0.f) ? o1 : expm1f(o1);
    o2 = (o2 > 0.f) ? o2 : expm1f(o2);
    o3 = (o3 > 0.f) ? o3 : expm1f(o3);
    float4* op = (float4*)(out + ((size_t)node << 8) + cb);
    float4 res = *op;                    // residual written by gemm epilogue
    res.x += o0; res.y += o1; res.z += o2; res.w += o3;
    *op = res;
  }
}

extern "C" void kernel_launch(void* const* d_in, const int* in_sizes, int n_in,
                              void* d_out, int out_size, void* d_ws, size_t ws_size,
                              hipStream_t stream) {
  const float* feat  = (const float*)d_in[0];
  const float* ew    = (const float*)d_in[1];
  const float* W_lin = (const float*)d_in[2];
  const float* att_l = (const float*)d_in[3];
  const float* att_r = (const float*)d_in[4];
  const float* W_res = (const float*)d_in[5];
  const int*   eidx  = (const int*)d_in[6];
  float* out = (float*)d_out;

  int N = in_sizes[0] / D_DIM;
  int E = in_sizes[1];
  int Np = (N + 255) & ~255;            // padded shard stride

  char* p = (char*)d_ws;
  auto alloc = [&](size_t bytes) {
    char* r = p; p += (bytes + 255) & ~(size_t)255; return r;
  };
  unsigned short* xbf  = (unsigned short*)alloc((size_t)N * 256 * 2);   // 25.6 MB
  unsigned short* fb   = (unsigned short*)alloc((size_t)N * 256 * 2);   // 25.6 MB
  float* alpha_l       = (float*)alloc((size_t)N * 8 * 4);
  float* alpha_r       = (float*)alloc((size_t)N * 8 * 4);
  unsigned short* Bt   = (unsigned short*)alloc((size_t)NPAD * D_DIM * 2);
  int*   row_ptr       = (int*)alloc((size_t)(N + 1) * 4);
  int*   cntS          = (int*)alloc((size_t)NSH * Np * 4);             // 1.6 MB
  int*   soffA         = (int*)alloc((size_t)NSH * Np * 4);             // 1.6 MB
  int*   rank          = (int*)alloc((size_t)E * 4);
  int*   bsum          = (int*)alloc(1024);
  int2*  pairs_sep     = (int2*)alloc((size_t)E * 8);                   // 12.8 MB
  bool sep_ok = ((size_t)((char*)(pairs_sep + E) - (char*)d_ws) <= ws_size);
  // fallback: alias pairs onto fb (dead after gemm; scatter runs after gemm)
  int2* pairs = sep_ok ? pairs_sep : (int2*)fb;

  int nb      = (N + 255) / 256;
  int nb_cvt  = (N * 256 / 8 + 255) / 256;
  int nb_prep = NPAD * D_DIM / 256;
  int nb_scat = (E + 255) / 256;
  int gx = (N + 127) / 128;               // 391; gemm tiles = gx*5, hist blocks = gx
  int echunk = (E + gx - 1) / gx;         // ~4093 edges per hist block

  hipMemsetAsync(cntS, 0, (size_t)NSH * Np * 4, stream);

  setup_cvt_prep<<<nb_cvt + nb_prep, 256, 0, stream>>>(
      feat, fb, W_lin, W_res, att_l, att_r, Bt, N * 256, nb_cvt);

  gemm_hist<<<gx * 6, 256, 0, stream>>>(
      fb, Bt, out, xbf, alpha_l, alpha_r, N, gx,
      eidx + E, cntS, rank, E, Np, echunk);

  scan_partial<<<nb, 256, 0, stream>>>(cntS, bsum, N, Np);
  scan_apply<<<nb, 256, 0, stream>>>(cntS, bsum, row_ptr, soffA, N, Np);

  scatter_kernel<<<nb_scat, 256, 0, stream>>>(eidx, ew, soffA, rank, pairs, E, Np);

  agg_kernel<<<(N + 1) / 2, 256, 0, stream>>>(row_ptr, pairs, alpha_l, alpha_r, xbf, out, N);
}